// Round 4
// baseline (533.005 us; speedup 1.0000x reference)
//
#include <hip/hip_runtime.h>
#include <stdint.h>

#define N_BATCH 8
#define A_ 3
#define H_ 336
#define W_ 336
#define HW_ (H_*W_)        // 112896
#define M_ (A_*HW_)        // 338688
#define K_TOP 2000
#define POST_N 1000
#define NMS_THR_ 0.7f
#define NEG_ (-1e9f)
#define VALID_THR_ (-5e8f)
#define CAND_CAP 4096
#define NBINS 4096
#define BIN_SHIFT 20       // top 12 bits: sign+exp+3 mantissa
#define HBLK 16            // histogram/compact blocks per batch
#define SEG_ (M_/HBLK)     // 21168
#define XCLIP 4.135166556742356f  // log(1000/16)

__device__ __forceinline__ unsigned int flip_key(float x) {
    unsigned int u = __float_as_uint(x);
    return (u & 0x80000000u) ? ~u : (u | 0x80000000u);
}
__device__ __forceinline__ float unflip_key(unsigned int k) {
    unsigned int u = (k & 0x80000000u) ? (k & 0x7fffffffu) : ~k;
    return __uint_as_float(u);
}

// ---------------- K1: per-block LDS histogram -> private u16 sub-hist (no global atomics) ----------------
__global__ __launch_bounds__(512) void k_hist(const float* __restrict__ logits,
                                              unsigned short* __restrict__ ghist) {
    __shared__ unsigned int h[NBINS];  // 16 KiB
    int n = blockIdx.y, b = blockIdx.x;
    for (int i = threadIdx.x; i < NBINS; i += 512) h[i] = 0;
    __syncthreads();
    const float4* lp = (const float4*)(logits + (size_t)n * M_ + (size_t)b * SEG_);
    const int nq = SEG_ / 4;                 // 5292
    for (int q = threadIdx.x; q < nq; q += 512) {
        float4 v = lp[q];
        atomicAdd(&h[flip_key(v.x) >> BIN_SHIFT], 1u);
        atomicAdd(&h[flip_key(v.y) >> BIN_SHIFT], 1u);
        atomicAdd(&h[flip_key(v.z) >> BIN_SHIFT], 1u);
        atomicAdd(&h[flip_key(v.w) >> BIN_SHIFT], 1u);
    }
    __syncthreads();
    unsigned short* gp = ghist + ((size_t)n * HBLK + b) * NBINS;
    for (int i = threadIdx.x; i < NBINS; i += 512) gp[i] = (unsigned short)h[i];
}

// ---------------- K1b: sum sub-hists, find threshold bin B per batch ----------------
__global__ __launch_bounds__(256) void k_scan(const unsigned short* __restrict__ ghist,
                                              unsigned int* __restrict__ thresh) {
    int n = blockIdx.x;
    int t = threadIdx.x;
    __shared__ unsigned int binsum[NBINS];
    __shared__ unsigned int part[256];
    __shared__ unsigned int scanb[256];
    const unsigned short* base = ghist + (size_t)n * HBLK * NBINS;
    for (int i = t; i < NBINS; i += 256) {
        unsigned int s = 0;
        #pragma unroll
        for (int b = 0; b < HBLK; ++b) s += base[(size_t)b * NBINS + i];
        binsum[i] = s;
    }
    __syncthreads();
    // chunk t covers bins [NBINS-16*(t+1), NBINS-16*t) — descending chunks
    int hi = NBINS - 16 * t;
    int lo = hi - 16;
    unsigned int s = 0;
    for (int b = lo; b < hi; ++b) s += binsum[b];
    part[t] = s;
    scanb[t] = s;
    __syncthreads();
    for (int off = 1; off < 256; off <<= 1) {
        unsigned int v = scanb[t];
        unsigned int addv = (t >= off) ? scanb[t - off] : 0u;
        __syncthreads();
        scanb[t] = v + addv;
        __syncthreads();
    }
    unsigned int incl = scanb[t];
    unsigned int prefix = incl - part[t];
    if (prefix < K_TOP && incl >= K_TOP) {
        unsigned int acc = prefix;
        for (int b = hi - 1; b >= lo; --b) {
            unsigned int c = binsum[b];
            if (acc + c >= K_TOP) {
                thresh[n] = (unsigned int)b;
                break;
            }
            acc += c;
        }
    }
}

// ---------------- K2: compact candidates via LDS buffer + 1 global atomic per block ----------------
__global__ __launch_bounds__(512) void k_compact(const float* __restrict__ logits,
                                                 const unsigned int* __restrict__ thresh,
                                                 unsigned int* __restrict__ cnt,
                                                 unsigned long long* __restrict__ cand) {
    __shared__ unsigned long long buf[CAND_CAP];  // 32 KiB
    __shared__ unsigned int lcnt;
    __shared__ unsigned int gbase;
    int n = blockIdx.y, b = blockIdx.x;
    unsigned int B = thresh[n];
    if (threadIdx.x == 0) lcnt = 0;
    __syncthreads();
    const int qbase = b * SEG_;
    const float4* lp = (const float4*)(logits + (size_t)n * M_ + (size_t)qbase);
    const int nq = SEG_ / 4;
    for (int q = threadIdx.x; q < nq; q += 512) {
        float4 v = lp[q];
        float vv[4] = {v.x, v.y, v.z, v.w};
        #pragma unroll
        for (int e = 0; e < 4; ++e) {
            unsigned int u = flip_key(vv[e]);
            if ((u >> BIN_SHIFT) >= B) {
                int qq = qbase + q * 4 + e;
                int a = qq / HW_;
                int hw = qq - a * HW_;
                unsigned int m = (unsigned int)(hw * A_ + a);  // score-order index
                unsigned int pos = atomicAdd(&lcnt, 1u);
                if (pos < CAND_CAP)
                    buf[pos] = ((unsigned long long)u << 32) | (unsigned int)(~m);
            }
        }
    }
    __syncthreads();
    unsigned int L = (lcnt < CAND_CAP) ? lcnt : CAND_CAP;
    if (threadIdx.x == 0) gbase = atomicAdd(&cnt[n], L);
    __syncthreads();
    unsigned long long* cp = cand + (size_t)n * CAND_CAP;
    for (unsigned int i = threadIdx.x; i < L; i += 512) {
        unsigned int pos = gbase + i;
        if (pos < CAND_CAP) cp[pos] = buf[i];
    }
}

// ---------------- K3: per-batch bitonic sort of 4096 (descending) + fused decode of top-2000 ----------------
__global__ __launch_bounds__(1024) void k_sort(const unsigned long long* __restrict__ cand,
                                               const unsigned int* __restrict__ cnt,
                                               const float* __restrict__ anchors,
                                               const float* __restrict__ breg,
                                               float4* __restrict__ boxes,
                                               float* __restrict__ scores,
                                               float* __restrict__ areas) {
    __shared__ unsigned long long sm[CAND_CAP];  // 32 KiB
    int n = blockIdx.x;
    unsigned int Cu = cnt[n];
    int C = (Cu < CAND_CAP) ? (int)Cu : CAND_CAP;
    const unsigned long long* cp = cand + (size_t)n * CAND_CAP;
    for (int i = threadIdx.x; i < CAND_CAP; i += 1024)
        sm[i] = (i < C) ? cp[i] : 0ull;
    __syncthreads();
    for (int k = 2; k <= CAND_CAP; k <<= 1) {
        for (int j = k >> 1; j > 0; j >>= 1) {
            for (int i = threadIdx.x; i < CAND_CAP; i += 1024) {
                int ixj = i ^ j;
                if (ixj > i) {
                    unsigned long long va = sm[i], vb = sm[ixj];
                    bool desc = ((i & k) == 0);
                    if (desc ? (va < vb) : (va > vb)) { sm[i] = vb; sm[ixj] = va; }
                }
            }
            __syncthreads();
        }
    }
    // fused decode + clip + validity for the top-2000
    for (int i = threadIdx.x; i < K_TOP; i += 1024) {
        unsigned long long kv = sm[i];
        unsigned int u = (unsigned int)(kv >> 32);
        unsigned int m = ~((unsigned int)kv);
        float logit = unflip_key(u);
        int a = (int)(m % 3u);
        int hw = (int)(m / 3u);
        float4 anc = ((const float4*)anchors)[(size_t)n * M_ + m];
        size_t rb = ((size_t)n * 12 + a * 4) * HW_ + hw;
        float dx = breg[rb];
        float dy = breg[rb + (size_t)HW_];
        float dw = breg[rb + (size_t)2 * HW_];
        float dh = breg[rb + (size_t)3 * HW_];
        float score = 1.0f / (1.0f + expf(-logit));
        float w = anc.z - anc.x + 1.0f;
        float h = anc.w - anc.y + 1.0f;
        float cx = anc.x + 0.5f * w;
        float cy = anc.y + 0.5f * h;
        dw = fminf(dw, XCLIP);
        dh = fminf(dh, XCLIP);
        float pcx = dx * w + cx;
        float pcy = dy * h + cy;
        float pw = expf(dw) * w;
        float ph = expf(dh) * h;
        float x1 = pcx - 0.5f * pw;
        float y1 = pcy - 0.5f * ph;
        float x2 = pcx + 0.5f * pw - 1.0f;
        float y2 = pcy + 0.5f * ph - 1.0f;
        x1 = fminf(fmaxf(x1, 0.0f), 1332.0f);
        y1 = fminf(fmaxf(y1, 0.0f), 799.0f);
        x2 = fminf(fmaxf(x2, 0.0f), 1332.0f);
        y2 = fminf(fmaxf(y2, 0.0f), 799.0f);
        float ww = x2 - x1 + 1.0f;
        float hh = y2 - y1 + 1.0f;
        bool keep = (ww >= 0.0f) && (hh >= 0.0f);  // MIN_SIZE = 0
        int g = n * K_TOP + i;
        boxes[g] = make_float4(x1, y1, x2, y2);
        scores[g] = keep ? score : NEG_;
        areas[g] = ww * hh;
    }
}

// ---------------- K5: all-pairs IoU edge flags (any overlap > thr) ----------------
#define JCHUNK 500
__global__ __launch_bounds__(256) void k_edges(const float4* __restrict__ boxes,
                                               const float* __restrict__ areas,
                                               unsigned int* __restrict__ eflag) {
    int n = blockIdx.z;
    int chunk = blockIdx.y;
    int i = blockIdx.x * 256 + threadIdx.x;
    __shared__ float4 jb[JCHUNK];
    __shared__ float ja[JCHUNK];
    int j0 = chunk * JCHUNK;
    for (int j = threadIdx.x; j < JCHUNK; j += 256) {
        jb[j] = boxes[(size_t)n * K_TOP + j0 + j];
        ja[j] = areas[(size_t)n * K_TOP + j0 + j];
    }
    __syncthreads();
    if (i >= K_TOP) return;
    float4 bi = boxes[(size_t)n * K_TOP + i];
    float ai = areas[(size_t)n * K_TOP + i];
    bool any = false;
    for (int j = 0; j < JCHUNK; ++j) {
        int jj = j0 + j;
        if (jj == i) continue;
        float4 bj = jb[j];
        float xx1 = fmaxf(bi.x, bj.x);
        float yy1 = fmaxf(bi.y, bj.y);
        float xx2 = fminf(bi.z, bj.z);
        float yy2 = fminf(bi.w, bj.w);
        float inter = fmaxf(xx2 - xx1 + 1.0f, 0.0f) * fmaxf(yy2 - yy1 + 1.0f, 0.0f);
        float iou = inter / (ai + ja[j] - inter);
        any |= (iou > NMS_THR_);
    }
    if (any) atomicOr(&eflag[(size_t)n * K_TOP + i], 1u);
}

// ---------------- K6: Jacobi fixed-point greedy NMS on involved subgraph + output ----------------
__global__ __launch_bounds__(256) void k_nms_out(const float4* __restrict__ boxes,
                                                 const float* __restrict__ scores,
                                                 const float* __restrict__ areas,
                                                 const unsigned int* __restrict__ eflag,
                                                 float* __restrict__ out) {
    int n = blockIdx.x;
    int tid = threadIdx.x;
    __shared__ float4 ibox[K_TOP];          // 32000 B
    __shared__ float iarea[K_TOP];          // 8000 B
    __shared__ unsigned short iidx[K_TOP];  // 4000 B
    __shared__ unsigned char val[K_TOP];
    __shared__ unsigned char cur[K_TOP];
    __shared__ unsigned char nxt[K_TOP];
    __shared__ unsigned char alive[K_TOP];
    __shared__ unsigned int scanbuf[256];
    __shared__ int invTot;
    __shared__ int changed;

    const float4* bb = boxes + (size_t)n * K_TOP;
    const float* ss = scores + (size_t)n * K_TOP;
    const float* aa = areas + (size_t)n * K_TOP;
    const unsigned int* ef = eflag + (size_t)n * K_TOP;

    // --- build involved list (order-preserving compaction of edge-flagged boxes) ---
    // 256 threads x 8 strides covers [0,2048) -- MUST clamp to K_TOP=2000.
    // (OOB LDS writes here were the R3 corruption bug.)
    int i0 = tid * 8;
    int iend = (i0 + 8 < K_TOP) ? (i0 + 8) : K_TOP;
    unsigned int c = 0;
    for (int i = i0; i < iend; ++i) {
        alive[i] = (ss[i] > VALID_THR_) ? 1 : 0;
        c += (ef[i] != 0u) ? 1u : 0u;
    }
    scanbuf[tid] = c;
    __syncthreads();
    for (int off = 1; off < 256; off <<= 1) {
        unsigned int v = scanbuf[tid];
        unsigned int addv = (tid >= off) ? scanbuf[tid - off] : 0u;
        __syncthreads();
        scanbuf[tid] = v + addv;
        __syncthreads();
    }
    unsigned int excl = scanbuf[tid] - c;
    if (tid == 255) invTot = (int)scanbuf[255];
    unsigned int p = excl;
    for (int i = i0; i < iend; ++i) {
        if (ef[i] != 0u) {
            iidx[p] = (unsigned short)i;
            ibox[p] = bb[i];
            iarea[p] = aa[i];
            unsigned char v = alive[i];
            val[p] = v;
            cur[p] = v;
            p++;
        }
    }
    __syncthreads();
    int IC = invTot;

    // --- Jacobi fixed-point: alive'[s] = val[s] && no earlier alive box overlaps ---
    while (true) {
        if (tid == 0) changed = 0;
        __syncthreads();
        for (int s = tid; s < IC; s += 256) {
            unsigned char a = val[s];
            if (a) {
                float4 bs = ibox[s];
                float as = iarea[s];
                for (int j = 0; j < s; ++j) {
                    if (!cur[j]) continue;
                    float4 bj = ibox[j];
                    float xx1 = fmaxf(bj.x, bs.x);
                    float yy1 = fmaxf(bj.y, bs.y);
                    float xx2 = fminf(bj.z, bs.z);
                    float yy2 = fminf(bj.w, bs.w);
                    float inter = fmaxf(xx2 - xx1 + 1.0f, 0.0f) * fmaxf(yy2 - yy1 + 1.0f, 0.0f);
                    float iou = inter / (iarea[j] + as - inter);
                    if (iou > NMS_THR_) { a = 0; break; }
                }
            }
            nxt[s] = a;
            if (a != cur[s]) changed = 1;  // benign race: all writers store 1
        }
        __syncthreads();
        for (int s = tid; s < IC; s += 256) cur[s] = nxt[s];
        int done = !changed;
        __syncthreads();
        if (done) break;
    }
    for (int s = tid; s < IC; s += 256) alive[iidx[s]] = cur[s];
    __syncthreads();

    // --- order-preserving compaction of survivors -> output rows ---
    unsigned int c2 = 0;
    for (int i = i0; i < iend; ++i) c2 += alive[i];
    scanbuf[tid] = c2;
    __syncthreads();
    for (int off = 1; off < 256; off <<= 1) {
        unsigned int v = scanbuf[tid];
        unsigned int addv = (tid >= off) ? scanbuf[tid - off] : 0u;
        __syncthreads();
        scanbuf[tid] = v + addv;
        __syncthreads();
    }
    unsigned int r = scanbuf[tid] - c2;
    unsigned int total = scanbuf[255];
    float* op = out + (size_t)n * POST_N * 5;
    for (int i = i0; i < iend; ++i) {
        if (alive[i]) {
            if (r < POST_N) {
                float4 b = bb[i];
                op[r * 5 + 0] = b.x;
                op[r * 5 + 1] = b.y;
                op[r * 5 + 2] = b.z;
                op[r * 5 + 3] = b.w;
                op[r * 5 + 4] = ss[i];
            }
            r++;
        }
    }
    unsigned int S = (total > POST_N) ? POST_N : total;
    for (unsigned int q = S + tid; q < POST_N; q += 256) {
        op[q * 5 + 0] = 0.0f;
        op[q * 5 + 1] = 0.0f;
        op[q * 5 + 2] = 0.0f;
        op[q * 5 + 3] = 0.0f;
        op[q * 5 + 4] = 0.0f;
    }
}

extern "C" void kernel_launch(void* const* d_in, const int* in_sizes, int n_in,
                              void* d_out, int out_size, void* d_ws, size_t ws_size,
                              hipStream_t stream) {
    const float* anchors = (const float*)d_in[0];
    const float* logits  = (const float*)d_in[1];
    const float* breg    = (const float*)d_in[2];
    float* out = (float*)d_out;
    char* ws = (char*)d_ws;

    // ws layout (bytes):
    // [0, 32)                cnt    : u32[8]              (zeroed)
    // [32, 64032)            eflag  : u32[8][2000]        (zeroed)
    // [64064, 1112640)       ghist  : u16[8][HBLK][4096]  (fully written, no zero)
    // [1112640, 1112672)     thresh : u32[8]
    // [1112672, 1374816)     cand   : u64[8][4096]
    // [1374816, 1630816)     boxes  : float4[8][2000]
    // [1630816, 1694816)     scores : f32[8][2000]
    // [1694816, 1758816)     areas  : f32[8][2000]
    unsigned int* cnt          = (unsigned int*)(ws);
    unsigned int* eflag        = (unsigned int*)(ws + 32);
    unsigned short* ghist      = (unsigned short*)(ws + 64064);
    unsigned int* thresh       = (unsigned int*)(ws + 1112640);
    unsigned long long* cand   = (unsigned long long*)(ws + 1112672);
    float4* boxes              = (float4*)(ws + 1374816);
    float* scores              = (float*)(ws + 1630816);
    float* areas               = (float*)(ws + 1694816);

    hipMemsetAsync(ws, 0, 64032, stream);

    k_hist<<<dim3(HBLK, 8), 512, 0, stream>>>(logits, ghist);
    k_scan<<<8, 256, 0, stream>>>(ghist, thresh);
    k_compact<<<dim3(HBLK, 8), 512, 0, stream>>>(logits, thresh, cnt, cand);
    k_sort<<<8, 1024, 0, stream>>>(cand, cnt, anchors, breg, boxes, scores, areas);
    k_edges<<<dim3(8, 4, 8), 256, 0, stream>>>(boxes, areas, eflag);
    k_nms_out<<<8, 256, 0, stream>>>(boxes, scores, areas, eflag, out);
}

// Round 5
// 488.887 us; speedup vs baseline: 1.0902x; 1.0902x over previous
//
#include <hip/hip_runtime.h>
#include <stdint.h>

#define N_BATCH 8
#define A_ 3
#define H_ 336
#define W_ 336
#define HW_ (H_*W_)        // 112896
#define M_ (A_*HW_)        // 338688
#define K_TOP 2000
#define POST_N 1000
#define NMS_THR_ 0.7f
#define NEG_ (-1e9f)
#define VALID_THR_ (-5e8f)
#define CAND_CAP 4096
#define NBINS 4096
#define BIN_SHIFT 20       // top 12 bits: sign+exp+3 mantissa
#define HBLK 16            // histogram/compact blocks per batch
#define SEG_ (M_/HBLK)     // 21168
#define XCLIP 4.135166556742356f  // log(1000/16)

#define NPAD 2048          // boxes padded to 32 chunks of 64
#define NW 32              // u64 words per adjacency row
#define NWP 33             // padded row stride in LDS (bank-conflict break)
#define NCHUNK 32

typedef unsigned long long u64;

__device__ __forceinline__ unsigned int flip_key(float x) {
    unsigned int u = __float_as_uint(x);
    return (u & 0x80000000u) ? ~u : (u | 0x80000000u);
}
__device__ __forceinline__ float unflip_key(unsigned int k) {
    unsigned int u = (k & 0x80000000u) ? (k & 0x7fffffffu) : ~k;
    return __uint_as_float(u);
}

// ---------------- K1: per-block LDS histogram -> private u16 sub-hist (no global atomics) ----------------
__global__ __launch_bounds__(512) void k_hist(const float* __restrict__ logits,
                                              unsigned short* __restrict__ ghist) {
    __shared__ unsigned int h[NBINS];  // 16 KiB
    int n = blockIdx.y, b = blockIdx.x;
    for (int i = threadIdx.x; i < NBINS; i += 512) h[i] = 0;
    __syncthreads();
    const float4* lp = (const float4*)(logits + (size_t)n * M_ + (size_t)b * SEG_);
    const int nq = SEG_ / 4;                 // 5292
    for (int q = threadIdx.x; q < nq; q += 512) {
        float4 v = lp[q];
        atomicAdd(&h[flip_key(v.x) >> BIN_SHIFT], 1u);
        atomicAdd(&h[flip_key(v.y) >> BIN_SHIFT], 1u);
        atomicAdd(&h[flip_key(v.z) >> BIN_SHIFT], 1u);
        atomicAdd(&h[flip_key(v.w) >> BIN_SHIFT], 1u);
    }
    __syncthreads();
    unsigned short* gp = ghist + ((size_t)n * HBLK + b) * NBINS;
    for (int i = threadIdx.x; i < NBINS; i += 512) gp[i] = (unsigned short)h[i];
}

// ---------------- K1b: sum sub-hists, find threshold bin B per batch ----------------
__global__ __launch_bounds__(256) void k_scan(const unsigned short* __restrict__ ghist,
                                              unsigned int* __restrict__ thresh) {
    int n = blockIdx.x;
    int t = threadIdx.x;
    __shared__ unsigned int binsum[NBINS];
    __shared__ unsigned int part[256];
    __shared__ unsigned int scanb[256];
    const unsigned short* base = ghist + (size_t)n * HBLK * NBINS;
    for (int i = t; i < NBINS; i += 256) {
        unsigned int s = 0;
        #pragma unroll
        for (int b = 0; b < HBLK; ++b) s += base[(size_t)b * NBINS + i];
        binsum[i] = s;
    }
    __syncthreads();
    // chunk t covers bins [NBINS-16*(t+1), NBINS-16*t) — descending chunks
    int hi = NBINS - 16 * t;
    int lo = hi - 16;
    unsigned int s = 0;
    for (int b = lo; b < hi; ++b) s += binsum[b];
    part[t] = s;
    scanb[t] = s;
    __syncthreads();
    for (int off = 1; off < 256; off <<= 1) {
        unsigned int v = scanb[t];
        unsigned int addv = (t >= off) ? scanb[t - off] : 0u;
        __syncthreads();
        scanb[t] = v + addv;
        __syncthreads();
    }
    unsigned int incl = scanb[t];
    unsigned int prefix = incl - part[t];
    if (prefix < K_TOP && incl >= K_TOP) {
        unsigned int acc = prefix;
        for (int b = hi - 1; b >= lo; --b) {
            unsigned int c = binsum[b];
            if (acc + c >= K_TOP) {
                thresh[n] = (unsigned int)b;
                break;
            }
            acc += c;
        }
    }
}

// ---------------- K2: compact candidates via LDS buffer + 1 global atomic per block ----------------
__global__ __launch_bounds__(512) void k_compact(const float* __restrict__ logits,
                                                 const unsigned int* __restrict__ thresh,
                                                 unsigned int* __restrict__ cnt,
                                                 u64* __restrict__ cand) {
    __shared__ u64 buf[CAND_CAP];  // 32 KiB
    __shared__ unsigned int lcnt;
    __shared__ unsigned int gbase;
    int n = blockIdx.y, b = blockIdx.x;
    unsigned int B = thresh[n];
    if (threadIdx.x == 0) lcnt = 0;
    __syncthreads();
    const int qbase = b * SEG_;
    const float4* lp = (const float4*)(logits + (size_t)n * M_ + (size_t)qbase);
    const int nq = SEG_ / 4;
    for (int q = threadIdx.x; q < nq; q += 512) {
        float4 v = lp[q];
        float vv[4] = {v.x, v.y, v.z, v.w};
        #pragma unroll
        for (int e = 0; e < 4; ++e) {
            unsigned int u = flip_key(vv[e]);
            if ((u >> BIN_SHIFT) >= B) {
                int qq = qbase + q * 4 + e;
                int a = qq / HW_;
                int hw = qq - a * HW_;
                unsigned int m = (unsigned int)(hw * A_ + a);  // score-order index
                unsigned int pos = atomicAdd(&lcnt, 1u);
                if (pos < CAND_CAP)
                    buf[pos] = ((u64)u << 32) | (unsigned int)(~m);
            }
        }
    }
    __syncthreads();
    unsigned int L = (lcnt < CAND_CAP) ? lcnt : CAND_CAP;
    if (threadIdx.x == 0) gbase = atomicAdd(&cnt[n], L);
    __syncthreads();
    u64* cp = cand + (size_t)n * CAND_CAP;
    for (unsigned int i = threadIdx.x; i < L; i += 512) {
        unsigned int pos = gbase + i;
        if (pos < CAND_CAP) cp[pos] = buf[i];
    }
}

// ---------------- K3: per-batch bitonic sort of 4096 (descending) + fused decode of top-2000 ----------------
__global__ __launch_bounds__(1024) void k_sort(const u64* __restrict__ cand,
                                               const unsigned int* __restrict__ cnt,
                                               const float* __restrict__ anchors,
                                               const float* __restrict__ breg,
                                               float4* __restrict__ boxes,
                                               float* __restrict__ scores,
                                               float* __restrict__ areas) {
    __shared__ u64 sm[CAND_CAP];  // 32 KiB
    int n = blockIdx.x;
    unsigned int Cu = cnt[n];
    int C = (Cu < CAND_CAP) ? (int)Cu : CAND_CAP;
    const u64* cp = cand + (size_t)n * CAND_CAP;
    for (int i = threadIdx.x; i < CAND_CAP; i += 1024)
        sm[i] = (i < C) ? cp[i] : 0ull;
    __syncthreads();
    for (int k = 2; k <= CAND_CAP; k <<= 1) {
        for (int j = k >> 1; j > 0; j >>= 1) {
            for (int i = threadIdx.x; i < CAND_CAP; i += 1024) {
                int ixj = i ^ j;
                if (ixj > i) {
                    u64 va = sm[i], vb = sm[ixj];
                    bool desc = ((i & k) == 0);
                    if (desc ? (va < vb) : (va > vb)) { sm[i] = vb; sm[ixj] = va; }
                }
            }
            __syncthreads();
        }
    }
    // fused decode + clip + validity for the top-2000
    for (int i = threadIdx.x; i < K_TOP; i += 1024) {
        u64 kv = sm[i];
        unsigned int u = (unsigned int)(kv >> 32);
        unsigned int m = ~((unsigned int)kv);
        float logit = unflip_key(u);
        int a = (int)(m % 3u);
        int hw = (int)(m / 3u);
        float4 anc = ((const float4*)anchors)[(size_t)n * M_ + m];
        size_t rb = ((size_t)n * 12 + a * 4) * HW_ + hw;
        float dx = breg[rb];
        float dy = breg[rb + (size_t)HW_];
        float dw = breg[rb + (size_t)2 * HW_];
        float dh = breg[rb + (size_t)3 * HW_];
        float score = 1.0f / (1.0f + expf(-logit));
        float w = anc.z - anc.x + 1.0f;
        float h = anc.w - anc.y + 1.0f;
        float cx = anc.x + 0.5f * w;
        float cy = anc.y + 0.5f * h;
        dw = fminf(dw, XCLIP);
        dh = fminf(dh, XCLIP);
        float pcx = dx * w + cx;
        float pcy = dy * h + cy;
        float pw = expf(dw) * w;
        float ph = expf(dh) * h;
        float x1 = pcx - 0.5f * pw;
        float y1 = pcy - 0.5f * ph;
        float x2 = pcx + 0.5f * pw - 1.0f;
        float y2 = pcy + 0.5f * ph - 1.0f;
        x1 = fminf(fmaxf(x1, 0.0f), 1332.0f);
        y1 = fminf(fmaxf(y1, 0.0f), 799.0f);
        x2 = fminf(fmaxf(x2, 0.0f), 1332.0f);
        y2 = fminf(fmaxf(y2, 0.0f), 799.0f);
        float ww = x2 - x1 + 1.0f;
        float hh = y2 - y1 + 1.0f;
        bool keep = (ww >= 0.0f) && (hh >= 0.0f);  // MIN_SIZE = 0
        int g = n * K_TOP + i;
        boxes[g] = make_float4(x1, y1, x2, y2);
        scores[g] = keep ? score : NEG_;
        areas[g] = ww * hh;
    }
}

// ---------------- K5: dense adjacency bitmask matrix: adj[n][i][w] bit b = IoU(i, 64w+b) > thr ----------------
#define JT 512   // j's per block tile (8 u64 words)
#define RT 64    // rows per block tile
__global__ __launch_bounds__(256) void k_edges(const float4* __restrict__ boxes,
                                               const float* __restrict__ areas,
                                               u64* __restrict__ adj) {
    __shared__ float4 jb[JT];
    __shared__ float ja[JT];
    int n = blockIdx.z;
    int r0 = blockIdx.y * RT;
    int j0 = blockIdx.x * JT;
    for (int j = threadIdx.x; j < JT; j += 256) {
        int jj = j0 + j;
        if (jj < K_TOP) {
            jb[j] = boxes[(size_t)n * K_TOP + jj];
            ja[j] = areas[(size_t)n * K_TOP + jj];
        } else {
            jb[j] = make_float4(-1e8f, -1e8f, -1e8f, -1e8f);  // IoU vs anything = 0
            ja[j] = 0.0f;
        }
    }
    __syncthreads();
    int i = r0 + (threadIdx.x >> 2);       // 4 threads per row
    if (i >= K_TOP) return;
    float4 bi = boxes[(size_t)n * K_TOP + i];
    float ai = areas[(size_t)n * K_TOP + i];
    #pragma unroll
    for (int rep = 0; rep < 2; ++rep) {
        int wl = (threadIdx.x & 3) + rep * 4;  // word-in-tile 0..7
        u64 bits = 0;
        int base = wl * 64;
        #pragma unroll 8
        for (int b = 0; b < 64; ++b) {
            float4 bj = jb[base + b];
            float xx1 = fmaxf(bi.x, bj.x);
            float yy1 = fmaxf(bi.y, bj.y);
            float xx2 = fminf(bi.z, bj.z);
            float yy2 = fminf(bi.w, bj.w);
            float inter = fmaxf(xx2 - xx1 + 1.0f, 0.0f) * fmaxf(yy2 - yy1 + 1.0f, 0.0f);
            float iou = inter / (ai + ja[base + b] - inter);
            bits |= ((u64)(iou > NMS_THR_)) << b;
        }
        adj[((size_t)n * NPAD + i) * NW + (j0 >> 6) + wl] = bits;
    }
}

// ---------------- K6: chunked bitmask greedy NMS resolve + order-preserving output ----------------
__global__ __launch_bounds__(256) void k_resolve(const float4* __restrict__ boxes,
                                                 const float* __restrict__ scores,
                                                 const u64* __restrict__ adj,
                                                 float* __restrict__ out) {
    __shared__ u64 rowbuf[2][64 * NWP];     // 2 x 16.9 KiB (padded rows)
    __shared__ float sls[NPAD];             // 8 KiB
    __shared__ unsigned char alive[NPAD];   // 2 KiB
    __shared__ unsigned int scanbuf[256];
    int n = blockIdx.x;
    int tid = threadIdx.x;
    const u64* ab = adj + (size_t)n * NPAD * NW;

    // stage scores, init alive
    for (int i = tid; i < NPAD; i += 256) {
        sls[i] = (i < K_TOP) ? scores[(size_t)n * K_TOP + i] : NEG_;
        alive[i] = 0;
    }
    // preload chunk 0 rows
    for (int idx = tid; idx < 64 * NW; idx += 256) {
        int k = idx >> 5, w = idx & 31;
        rowbuf[0][k * NWP + w] = ab[(size_t)k * NW + w];
    }
    __syncthreads();

    u64 sup = 0;   // lane w (w<32) of wave 0 holds suppressed-mask word w
    for (int c = 0; c < NCHUNK; ++c) {
        int cur = c & 1, nxt = cur ^ 1;
        // waves 1..3: prefetch chunk c+1 rows into the other buffer
        if (tid >= 64 && c < NCHUNK - 1) {
            int rbase = (c + 1) * 64;
            for (int idx = tid - 64; idx < 64 * NW; idx += 192) {
                int k = idx >> 5, w = idx & 31;
                rowbuf[nxt][k * NWP + w] = ab[(size_t)(rbase + k) * NW + w];
            }
        }
        if (tid < 64) {  // wave 0: resolve chunk c
            int k = tid;
            int gi = c * 64 + k;
            u64 diag = rowbuf[cur][k * NWP + c];       // row gi, word c (intra-chunk bits)
            float sc = sls[gi];
            u64 invmask = __ballot(sc <= VALID_THR_ || gi >= K_TOP);
            u64 supc = __shfl(sup, c, 64);             // incoming suppressed bits for this chunk
            u64 dead = supc | invmask;                 // replicated across lanes
            u64 aliveM = 0;
            for (int kk = 0; kk < 64; ++kk) {
                u64 rk = __shfl(diag, kk, 64);
                if (!((dead >> kk) & 1ull)) {
                    aliveM |= 1ull << kk;
                    dead |= rk & ~((2ull << kk) - 1ull);  // suppress only j > kk (kk=63: mask=0)
                }
            }
            alive[gi] = (unsigned char)((aliveM >> k) & 1ull);
            if (k < 32) {  // OR selected rows into the running suppressed mask
                u64 m = aliveM;
                while (m) {
                    int kk = __ffsll((unsigned long long)m) - 1;
                    m &= m - 1;
                    sup |= rowbuf[cur][kk * NWP + k];
                }
            }
        }
        __syncthreads();
    }

    // --- order-preserving compaction of survivors -> output rows ---
    int i0 = tid * 8;   // covers [0,2048); alive[>=2000]=0, arrays sized NPAD -> in bounds
    unsigned int c2 = 0;
    for (int i = i0; i < i0 + 8; ++i) c2 += alive[i];
    scanbuf[tid] = c2;
    __syncthreads();
    for (int off = 1; off < 256; off <<= 1) {
        unsigned int v = scanbuf[tid];
        unsigned int addv = (tid >= off) ? scanbuf[tid - off] : 0u;
        __syncthreads();
        scanbuf[tid] = v + addv;
        __syncthreads();
    }
    unsigned int r = scanbuf[tid] - c2;
    unsigned int total = scanbuf[255];
    float* op = out + (size_t)n * POST_N * 5;
    const float4* bb = boxes + (size_t)n * K_TOP;
    for (int i = i0; i < i0 + 8; ++i) {
        if (alive[i]) {
            if (r < POST_N) {
                float4 b = bb[i];
                op[r * 5 + 0] = b.x;
                op[r * 5 + 1] = b.y;
                op[r * 5 + 2] = b.z;
                op[r * 5 + 3] = b.w;
                op[r * 5 + 4] = sls[i];
            }
            r++;
        }
    }
    unsigned int S = (total > POST_N) ? POST_N : total;
    for (unsigned int q = S + tid; q < POST_N; q += 256) {
        op[q * 5 + 0] = 0.0f;
        op[q * 5 + 1] = 0.0f;
        op[q * 5 + 2] = 0.0f;
        op[q * 5 + 3] = 0.0f;
        op[q * 5 + 4] = 0.0f;
    }
}

extern "C" void kernel_launch(void* const* d_in, const int* in_sizes, int n_in,
                              void* d_out, int out_size, void* d_ws, size_t ws_size,
                              hipStream_t stream) {
    const float* anchors = (const float*)d_in[0];
    const float* logits  = (const float*)d_in[1];
    const float* breg    = (const float*)d_in[2];
    float* out = (float*)d_out;
    char* ws = (char*)d_ws;

    // ws layout (bytes):
    // [0, 32)               cnt    : u32[8]              (zeroed)
    // [64, 96)              thresh : u32[8]              (written by k_scan)
    // [128, 1048704)        ghist  : u16[8][HBLK][4096]  (fully written)
    // [1048704, 1310848)    cand   : u64[8][4096]
    // [1310848, 1566848)    boxes  : float4[8][2000]
    // [1566848, 1630848)    scores : f32[8][2000]
    // [1630848, 1694848)    areas  : f32[8][2000]
    // [1703936, 5898240)    adj    : u64[8][2048][32]    (rows >=2000 unwritten, never used)
    unsigned int* cnt     = (unsigned int*)(ws);
    unsigned int* thresh  = (unsigned int*)(ws + 64);
    unsigned short* ghist = (unsigned short*)(ws + 128);
    u64* cand             = (u64*)(ws + 1048704);
    float4* boxes         = (float4*)(ws + 1310848);
    float* scores         = (float*)(ws + 1566848);
    float* areas          = (float*)(ws + 1630848);
    u64* adj              = (u64*)(ws + 1703936);

    hipMemsetAsync(ws, 0, 96, stream);

    k_hist<<<dim3(HBLK, 8), 512, 0, stream>>>(logits, ghist);
    k_scan<<<8, 256, 0, stream>>>(ghist, thresh);
    k_compact<<<dim3(HBLK, 8), 512, 0, stream>>>(logits, thresh, cnt, cand);
    k_sort<<<8, 1024, 0, stream>>>(cand, cnt, anchors, breg, boxes, scores, areas);
    k_edges<<<dim3(NPAD / JT, NPAD / RT, 8), 256, 0, stream>>>(boxes, areas, adj);
    k_resolve<<<8, 256, 0, stream>>>(boxes, scores, adj, out);
}

// Round 6
// 348.625 us; speedup vs baseline: 1.5289x; 1.4023x over previous
//
#include <hip/hip_runtime.h>
#include <stdint.h>

#define N_BATCH 8
#define A_ 3
#define H_ 336
#define W_ 336
#define HW_ (H_*W_)        // 112896
#define M_ (A_*HW_)        // 338688
#define K_TOP 2000
#define POST_N 1000
#define NMS_THR_ 0.7f
#define NEG_ (-1e9f)
#define VALID_THR_ (-5e8f)
#define CAND_CAP 4096
#define NBINS 4096
#define BIN_SHIFT 20       // top 12 bits: sign+exp+3 mantissa
#define HBLK 32            // histogram/compact blocks per batch (256 blocks total)
#define SEG_ (M_/HBLK)     // 10584
#define XCLIP 4.135166556742356f  // log(1000/16)

#define NPAD 2048          // boxes padded to 32 chunks of 64
#define NW 32              // u64 words per adjacency row
#define NWP 33             // padded row stride in LDS (bank-conflict break)
#define NCHUNK 32

typedef unsigned long long u64;

__device__ __forceinline__ unsigned int flip_key(float x) {
    unsigned int u = __float_as_uint(x);
    return (u & 0x80000000u) ? ~u : (u | 0x80000000u);
}
__device__ __forceinline__ float unflip_key(unsigned int k) {
    unsigned int u = (k & 0x80000000u) ? (k & 0x7fffffffu) : ~k;
    return __uint_as_float(u);
}

// ---------------- K1: per-block LDS histogram -> private u16 sub-hist (no global atomics) ----------------
__global__ __launch_bounds__(512) void k_hist(const float* __restrict__ logits,
                                              unsigned short* __restrict__ ghist) {
    __shared__ unsigned int h[NBINS];  // 16 KiB
    int n = blockIdx.y, b = blockIdx.x;
    for (int i = threadIdx.x; i < NBINS; i += 512) h[i] = 0;
    __syncthreads();
    const float4* lp = (const float4*)(logits + (size_t)n * M_ + (size_t)b * SEG_);
    const int nq = SEG_ / 4;                 // 2646
    for (int q = threadIdx.x; q < nq; q += 512) {
        float4 v = lp[q];
        atomicAdd(&h[flip_key(v.x) >> BIN_SHIFT], 1u);
        atomicAdd(&h[flip_key(v.y) >> BIN_SHIFT], 1u);
        atomicAdd(&h[flip_key(v.z) >> BIN_SHIFT], 1u);
        atomicAdd(&h[flip_key(v.w) >> BIN_SHIFT], 1u);
    }
    __syncthreads();
    unsigned short* gp = ghist + ((size_t)n * HBLK + b) * NBINS;
    for (int i = threadIdx.x; i < NBINS; i += 512) gp[i] = (unsigned short)h[i];
}

// ---------------- K1b: sum sub-hists, find threshold bin B per batch ----------------
__global__ __launch_bounds__(256) void k_scan(const unsigned short* __restrict__ ghist,
                                              unsigned int* __restrict__ thresh) {
    int n = blockIdx.x;
    int t = threadIdx.x;
    __shared__ unsigned int binsum[NBINS];
    __shared__ unsigned int part[256];
    __shared__ unsigned int scanb[256];
    const unsigned short* base = ghist + (size_t)n * HBLK * NBINS;
    for (int i = t; i < NBINS; i += 256) {
        unsigned int s = 0;
        #pragma unroll 8
        for (int b = 0; b < HBLK; ++b) s += base[(size_t)b * NBINS + i];
        binsum[i] = s;
    }
    __syncthreads();
    // chunk t covers bins [NBINS-16*(t+1), NBINS-16*t) — descending chunks
    int hi = NBINS - 16 * t;
    int lo = hi - 16;
    unsigned int s = 0;
    for (int b = lo; b < hi; ++b) s += binsum[b];
    part[t] = s;
    scanb[t] = s;
    __syncthreads();
    for (int off = 1; off < 256; off <<= 1) {
        unsigned int v = scanb[t];
        unsigned int addv = (t >= off) ? scanb[t - off] : 0u;
        __syncthreads();
        scanb[t] = v + addv;
        __syncthreads();
    }
    unsigned int incl = scanb[t];
    unsigned int prefix = incl - part[t];
    if (prefix < K_TOP && incl >= K_TOP) {
        unsigned int acc = prefix;
        for (int b = hi - 1; b >= lo; --b) {
            unsigned int c = binsum[b];
            if (acc + c >= K_TOP) {
                thresh[n] = (unsigned int)b;
                break;
            }
            acc += c;
        }
    }
}

// ---------------- K2: compact candidates via LDS buffer + 1 global atomic per block ----------------
__global__ __launch_bounds__(512) void k_compact(const float* __restrict__ logits,
                                                 const unsigned int* __restrict__ thresh,
                                                 unsigned int* __restrict__ cnt,
                                                 u64* __restrict__ cand) {
    __shared__ u64 buf[CAND_CAP];  // 32 KiB
    __shared__ unsigned int lcnt;
    __shared__ unsigned int gbase;
    int n = blockIdx.y, b = blockIdx.x;
    unsigned int B = thresh[n];
    if (threadIdx.x == 0) lcnt = 0;
    __syncthreads();
    const int qbase = b * SEG_;
    const float4* lp = (const float4*)(logits + (size_t)n * M_ + (size_t)qbase);
    const int nq = SEG_ / 4;
    for (int q = threadIdx.x; q < nq; q += 512) {
        float4 v = lp[q];
        float vv[4] = {v.x, v.y, v.z, v.w};
        #pragma unroll
        for (int e = 0; e < 4; ++e) {
            unsigned int u = flip_key(vv[e]);
            if ((u >> BIN_SHIFT) >= B) {
                int qq = qbase + q * 4 + e;
                int a = qq / HW_;
                int hw = qq - a * HW_;
                unsigned int m = (unsigned int)(hw * A_ + a);  // score-order index
                unsigned int pos = atomicAdd(&lcnt, 1u);
                if (pos < CAND_CAP)
                    buf[pos] = ((u64)u << 32) | (unsigned int)(~m);
            }
        }
    }
    __syncthreads();
    unsigned int L = (lcnt < CAND_CAP) ? lcnt : CAND_CAP;
    if (threadIdx.x == 0) gbase = atomicAdd(&cnt[n], L);
    __syncthreads();
    u64* cp = cand + (size_t)n * CAND_CAP;
    for (unsigned int i = threadIdx.x; i < L; i += 512) {
        unsigned int pos = gbase + i;
        if (pos < CAND_CAP) cp[pos] = buf[i];
    }
}

// ---------------- K3: per-batch bitonic sort of 4096 (descending) + fused decode of top-2000 ----------------
__global__ __launch_bounds__(1024) void k_sort(const u64* __restrict__ cand,
                                               const unsigned int* __restrict__ cnt,
                                               const float* __restrict__ anchors,
                                               const float* __restrict__ breg,
                                               float4* __restrict__ boxes,
                                               float* __restrict__ scores,
                                               float* __restrict__ areas) {
    __shared__ u64 sm[CAND_CAP];  // 32 KiB
    int n = blockIdx.x;
    unsigned int Cu = cnt[n];
    int C = (Cu < CAND_CAP) ? (int)Cu : CAND_CAP;
    const u64* cp = cand + (size_t)n * CAND_CAP;
    for (int i = threadIdx.x; i < CAND_CAP; i += 1024)
        sm[i] = (i < C) ? cp[i] : 0ull;
    __syncthreads();
    for (int k = 2; k <= CAND_CAP; k <<= 1) {
        for (int j = k >> 1; j > 0; j >>= 1) {
            for (int i = threadIdx.x; i < CAND_CAP; i += 1024) {
                int ixj = i ^ j;
                if (ixj > i) {
                    u64 va = sm[i], vb = sm[ixj];
                    bool desc = ((i & k) == 0);
                    if (desc ? (va < vb) : (va > vb)) { sm[i] = vb; sm[ixj] = va; }
                }
            }
            __syncthreads();
        }
    }
    // fused decode + clip + validity for the top-2000
    for (int i = threadIdx.x; i < K_TOP; i += 1024) {
        u64 kv = sm[i];
        unsigned int u = (unsigned int)(kv >> 32);
        unsigned int m = ~((unsigned int)kv);
        float logit = unflip_key(u);
        int a = (int)(m % 3u);
        int hw = (int)(m / 3u);
        float4 anc = ((const float4*)anchors)[(size_t)n * M_ + m];
        size_t rb = ((size_t)n * 12 + a * 4) * HW_ + hw;
        float dx = breg[rb];
        float dy = breg[rb + (size_t)HW_];
        float dw = breg[rb + (size_t)2 * HW_];
        float dh = breg[rb + (size_t)3 * HW_];
        float score = 1.0f / (1.0f + expf(-logit));
        float w = anc.z - anc.x + 1.0f;
        float h = anc.w - anc.y + 1.0f;
        float cx = anc.x + 0.5f * w;
        float cy = anc.y + 0.5f * h;
        dw = fminf(dw, XCLIP);
        dh = fminf(dh, XCLIP);
        float pcx = dx * w + cx;
        float pcy = dy * h + cy;
        float pw = expf(dw) * w;
        float ph = expf(dh) * h;
        float x1 = pcx - 0.5f * pw;
        float y1 = pcy - 0.5f * ph;
        float x2 = pcx + 0.5f * pw - 1.0f;
        float y2 = pcy + 0.5f * ph - 1.0f;
        x1 = fminf(fmaxf(x1, 0.0f), 1332.0f);
        y1 = fminf(fmaxf(y1, 0.0f), 799.0f);
        x2 = fminf(fmaxf(x2, 0.0f), 1332.0f);
        y2 = fminf(fmaxf(y2, 0.0f), 799.0f);
        float ww = x2 - x1 + 1.0f;
        float hh = y2 - y1 + 1.0f;
        bool keep = (ww >= 0.0f) && (hh >= 0.0f);  // MIN_SIZE = 0
        int g = n * K_TOP + i;
        boxes[g] = make_float4(x1, y1, x2, y2);
        scores[g] = keep ? score : NEG_;
        areas[g] = ww * hh;
    }
}

// ---------------- K5: dense adjacency bitmask: adj[n][i][w] bit b = IoU(i, 64w+b) > thr ----------------
// NOTE: IoU is computed with fully commutative float ops -> matrix is bitwise symmetric.
// k_resolve depends on this (uses rows as columns).
#define JT 512   // j's per block tile (8 u64 words)
#define RT 64    // rows per block tile
__global__ __launch_bounds__(256) void k_edges(const float4* __restrict__ boxes,
                                               const float* __restrict__ areas,
                                               u64* __restrict__ adj) {
    __shared__ float4 jb[JT];
    __shared__ float ja[JT];
    int n = blockIdx.z;
    int r0 = blockIdx.y * RT;
    int j0 = blockIdx.x * JT;
    for (int j = threadIdx.x; j < JT; j += 256) {
        int jj = j0 + j;
        if (jj < K_TOP) {
            jb[j] = boxes[(size_t)n * K_TOP + jj];
            ja[j] = areas[(size_t)n * K_TOP + jj];
        } else {
            jb[j] = make_float4(-1e8f, -1e8f, -1e8f, -1e8f);  // IoU vs anything = 0
            ja[j] = 0.0f;
        }
    }
    __syncthreads();
    int i = r0 + (threadIdx.x >> 2);       // 4 threads per row
    if (i >= K_TOP) return;
    float4 bi = boxes[(size_t)n * K_TOP + i];
    float ai = areas[(size_t)n * K_TOP + i];
    #pragma unroll
    for (int rep = 0; rep < 2; ++rep) {
        int wl = (threadIdx.x & 3) + rep * 4;  // word-in-tile 0..7
        u64 bits = 0;
        int base = wl * 64;
        #pragma unroll 8
        for (int b = 0; b < 64; ++b) {
            float4 bj = jb[base + b];
            float xx1 = fmaxf(bi.x, bj.x);
            float yy1 = fmaxf(bi.y, bj.y);
            float xx2 = fminf(bi.z, bj.z);
            float yy2 = fminf(bi.w, bj.w);
            float inter = fmaxf(xx2 - xx1 + 1.0f, 0.0f) * fmaxf(yy2 - yy1 + 1.0f, 0.0f);
            float iou = inter / (ai + ja[base + b] - inter);
            bits |= ((u64)(iou > NMS_THR_)) << b;
        }
        adj[((size_t)n * NPAD + i) * NW + (j0 >> 6) + wl] = bits;
    }
}

// ---------------- K6: chunked greedy NMS, ballot-Jacobi per chunk (no serial shfl chain) ----------------
__global__ __launch_bounds__(256) void k_resolve(const float4* __restrict__ boxes,
                                                 const float* __restrict__ scores,
                                                 const u64* __restrict__ adj,
                                                 float* __restrict__ out) {
    __shared__ u64 rowbuf[2][64 * NWP];     // 2 x 16.9 KiB (padded rows)
    __shared__ float sls[NPAD];             // 8 KiB
    __shared__ unsigned char alive[NPAD];   // 2 KiB  (indices >= K_TOP stay 0)
    __shared__ unsigned int scanbuf[256];
    int n = blockIdx.x;
    int tid = threadIdx.x;
    const u64* ab = adj + (size_t)n * NPAD * NW;

    for (int i = tid; i < NPAD; i += 256) {
        sls[i] = (i < K_TOP) ? scores[(size_t)n * K_TOP + i] : NEG_;
        alive[i] = 0;
    }
    // preload chunk 0 rows
    for (int idx = tid; idx < 64 * NW; idx += 256) {
        int k = idx >> 5, w = idx & 31;
        rowbuf[0][k * NWP + w] = ab[(size_t)k * NW + w];
    }
    __syncthreads();

    u64 sup = 0;   // lane w (w<32) of wave 0 holds suppressed-mask word w
    for (int c = 0; c < NCHUNK; ++c) {
        int cur = c & 1, nxt = cur ^ 1;
        // waves 1..3: prefetch chunk c+1 rows into the other buffer
        if (tid >= 64 && c < NCHUNK - 1) {
            int rbase = (c + 1) * 64;
            for (int idx = tid - 64; idx < 64 * NW; idx += 192) {
                int k = idx >> 5, w = idx & 31;
                rowbuf[nxt][k * NWP + w] = ab[(size_t)(rbase + k) * NW + w];
            }
        }
        if (tid < 64) {  // wave 0: resolve chunk c
            int k = tid;
            int gi = c * 64 + k;
            // symmetric adjacency: row gi's word c == column k of the 64x64 diagonal block
            u64 colk = rowbuf[cur][k * NWP + c];
            u64 supc = __shfl(sup, c, 64);             // incoming suppressed bits for this chunk
            bool validk = (sls[gi] > VALID_THR_) && !((supc >> k) & 1ull);
            u64 below = (k == 0) ? 0ull : ((1ull << k) - 1ull);
            u64 rel = colk & below;                    // earlier-in-chunk neighbors (self bit excluded)
            // ballot-Jacobi on a_k = valid_k && !(aliveMask & rel): recurrence is well-founded
            // in k, so after t iters all depth<=t entries are final; mask-stable => unique fixed
            // point == greedy result. Each iter: 1 ballot + ~6 VALU.
            bool a = validk;
            u64 am = __ballot(a);
            while (true) {
                bool anew = validk && ((am & rel) == 0ull);
                u64 am2 = __ballot(anew);
                if (am2 == am) { a = anew; break; }
                am = am2;
            }
            alive[gi] = a ? 1 : 0;
            if (k < 32) {  // OR alive rows into the running suppressed mask (pipelined LDS reads)
                u64 m = am;
                while (m) {
                    int kk = __ffsll((unsigned long long)m) - 1;
                    m &= m - 1;
                    sup |= rowbuf[cur][kk * NWP + k];
                }
            }
        }
        __syncthreads();
    }

    // --- order-preserving compaction of survivors -> output rows ---
    // i0 covers [0,2048): all arrays are NPAD-sized and alive[>=K_TOP]==0 (R3 lesson).
    int i0 = tid * 8;
    unsigned int c2 = 0;
    for (int i = i0; i < i0 + 8; ++i) c2 += alive[i];
    scanbuf[tid] = c2;
    __syncthreads();
    for (int off = 1; off < 256; off <<= 1) {
        unsigned int v = scanbuf[tid];
        unsigned int addv = (tid >= off) ? scanbuf[tid - off] : 0u;
        __syncthreads();
        scanbuf[tid] = v + addv;
        __syncthreads();
    }
    unsigned int r = scanbuf[tid] - c2;
    unsigned int total = scanbuf[255];
    float* op = out + (size_t)n * POST_N * 5;
    const float4* bb = boxes + (size_t)n * K_TOP;
    for (int i = i0; i < i0 + 8; ++i) {
        if (alive[i]) {
            if (r < POST_N) {
                float4 b = bb[i];
                op[r * 5 + 0] = b.x;
                op[r * 5 + 1] = b.y;
                op[r * 5 + 2] = b.z;
                op[r * 5 + 3] = b.w;
                op[r * 5 + 4] = sls[i];
            }
            r++;
        }
    }
    unsigned int S = (total > POST_N) ? POST_N : total;
    for (unsigned int q = S + tid; q < POST_N; q += 256) {
        op[q * 5 + 0] = 0.0f;
        op[q * 5 + 1] = 0.0f;
        op[q * 5 + 2] = 0.0f;
        op[q * 5 + 3] = 0.0f;
        op[q * 5 + 4] = 0.0f;
    }
}

extern "C" void kernel_launch(void* const* d_in, const int* in_sizes, int n_in,
                              void* d_out, int out_size, void* d_ws, size_t ws_size,
                              hipStream_t stream) {
    const float* anchors = (const float*)d_in[0];
    const float* logits  = (const float*)d_in[1];
    const float* breg    = (const float*)d_in[2];
    float* out = (float*)d_out;
    char* ws = (char*)d_ws;

    // ws layout (bytes) — adj ALIASES ghist+cand (both dead before k_edges writes adj):
    // [0, 32)               cnt    : u32[8]              (zeroed each launch)
    // [64, 96)              thresh : u32[8]              (written by k_scan)
    // [128, 2097280)        ghist  : u16[8][HBLK=32][4096]   \ dead after k_scan / k_sort
    // [2097280, 2359424)    cand   : u64[8][4096]            /
    // [128, 4194432)        adj    : u64[8][2048][32]    (written by k_edges after k_sort)
    // [4194432, 4450432)    boxes  : float4[8][2000]
    // [4450432, 4514432)    scores : f32[8][2000]
    // [4514432, 4578432)    areas  : f32[8][2000]
    unsigned int* cnt     = (unsigned int*)(ws);
    unsigned int* thresh  = (unsigned int*)(ws + 64);
    unsigned short* ghist = (unsigned short*)(ws + 128);
    u64* cand             = (u64*)(ws + 2097280);
    u64* adj              = (u64*)(ws + 128);
    float4* boxes         = (float4*)(ws + 4194432);
    float* scores         = (float*)(ws + 4450432);
    float* areas          = (float*)(ws + 4514432);

    hipMemsetAsync(ws, 0, 96, stream);

    k_hist<<<dim3(HBLK, 8), 512, 0, stream>>>(logits, ghist);
    k_scan<<<8, 256, 0, stream>>>(ghist, thresh);
    k_compact<<<dim3(HBLK, 8), 512, 0, stream>>>(logits, thresh, cnt, cand);
    k_sort<<<8, 1024, 0, stream>>>(cand, cnt, anchors, breg, boxes, scores, areas);
    k_edges<<<dim3(NPAD / JT, NPAD / RT, 8), 256, 0, stream>>>(boxes, areas, adj);
    k_resolve<<<8, 256, 0, stream>>>(boxes, scores, adj, out);
}

// Round 7
// 327.306 us; speedup vs baseline: 1.6285x; 1.0651x over previous
//
#include <hip/hip_runtime.h>
#include <stdint.h>

#define N_BATCH 8
#define A_ 3
#define H_ 336
#define W_ 336
#define HW_ (H_*W_)        // 112896
#define M_ (A_*HW_)        // 338688
#define K_TOP 2000
#define POST_N 1000
#define NMS_THR_ 0.7f
#define NEG_ (-1e9f)
#define VALID_THR_ (-5e8f)
#define CAND_CAP 4096
#define NBINS 4096
#define BIN_SHIFT 20       // top 12 bits: sign+exp+3 mantissa
#define HBLK 32            // histogram/compact blocks per batch (256 blocks total)
#define SEG_ (M_/HBLK)     // 10584
#define XCLIP 4.135166556742356f  // log(1000/16)

#define NPAD 2048          // boxes padded to 32 chunks of 64
#define NW 32              // u64 words per adjacency row
#define NWP 33             // padded row stride in LDS (bank-conflict break)
#define NCHUNK 32

typedef unsigned long long u64;

__device__ __forceinline__ unsigned int flip_key(float x) {
    unsigned int u = __float_as_uint(x);
    return (u & 0x80000000u) ? ~u : (u | 0x80000000u);
}
__device__ __forceinline__ float unflip_key(unsigned int k) {
    unsigned int u = (k & 0x80000000u) ? (k & 0x7fffffffu) : ~k;
    return __uint_as_float(u);
}

// ---------------- K1: per-block LDS histogram -> private u16 sub-hist (no global atomics) ----------------
__global__ __launch_bounds__(512) void k_hist(const float* __restrict__ logits,
                                              unsigned short* __restrict__ ghist) {
    __shared__ unsigned int h[NBINS];  // 16 KiB
    int n = blockIdx.y, b = blockIdx.x;
    for (int i = threadIdx.x; i < NBINS; i += 512) h[i] = 0;
    __syncthreads();
    const float4* lp = (const float4*)(logits + (size_t)n * M_ + (size_t)b * SEG_);
    const int nq = SEG_ / 4;                 // 2646
    for (int q = threadIdx.x; q < nq; q += 512) {
        float4 v = lp[q];
        atomicAdd(&h[flip_key(v.x) >> BIN_SHIFT], 1u);
        atomicAdd(&h[flip_key(v.y) >> BIN_SHIFT], 1u);
        atomicAdd(&h[flip_key(v.z) >> BIN_SHIFT], 1u);
        atomicAdd(&h[flip_key(v.w) >> BIN_SHIFT], 1u);
    }
    __syncthreads();
    unsigned short* gp = ghist + ((size_t)n * HBLK + b) * NBINS;
    for (int i = threadIdx.x; i < NBINS; i += 512) gp[i] = (unsigned short)h[i];
}

// ---------------- K1b: sum sub-hists, find threshold bin B per batch ----------------
__global__ __launch_bounds__(256) void k_scan(const unsigned short* __restrict__ ghist,
                                              unsigned int* __restrict__ thresh) {
    int n = blockIdx.x;
    int t = threadIdx.x;
    __shared__ unsigned int binsum[NBINS];
    __shared__ unsigned int part[256];
    __shared__ unsigned int scanb[256];
    const unsigned short* base = ghist + (size_t)n * HBLK * NBINS;
    for (int i = t; i < NBINS; i += 256) {
        unsigned int s = 0;
        #pragma unroll 8
        for (int b = 0; b < HBLK; ++b) s += base[(size_t)b * NBINS + i];
        binsum[i] = s;
    }
    __syncthreads();
    // chunk t covers bins [NBINS-16*(t+1), NBINS-16*t) — descending chunks
    int hi = NBINS - 16 * t;
    int lo = hi - 16;
    unsigned int s = 0;
    for (int b = lo; b < hi; ++b) s += binsum[b];
    part[t] = s;
    scanb[t] = s;
    __syncthreads();
    for (int off = 1; off < 256; off <<= 1) {
        unsigned int v = scanb[t];
        unsigned int addv = (t >= off) ? scanb[t - off] : 0u;
        __syncthreads();
        scanb[t] = v + addv;
        __syncthreads();
    }
    unsigned int incl = scanb[t];
    unsigned int prefix = incl - part[t];
    if (prefix < K_TOP && incl >= K_TOP) {
        unsigned int acc = prefix;
        for (int b = hi - 1; b >= lo; --b) {
            unsigned int c = binsum[b];
            if (acc + c >= K_TOP) {
                thresh[n] = (unsigned int)b;
                break;
            }
            acc += c;
        }
    }
}

// ---------------- K2: compact candidates via LDS buffer + 1 global atomic per block ----------------
__global__ __launch_bounds__(512) void k_compact(const float* __restrict__ logits,
                                                 const unsigned int* __restrict__ thresh,
                                                 unsigned int* __restrict__ cnt,
                                                 u64* __restrict__ cand) {
    __shared__ u64 buf[CAND_CAP];  // 32 KiB
    __shared__ unsigned int lcnt;
    __shared__ unsigned int gbase;
    int n = blockIdx.y, b = blockIdx.x;
    unsigned int B = thresh[n];
    if (threadIdx.x == 0) lcnt = 0;
    __syncthreads();
    const int qbase = b * SEG_;
    const float4* lp = (const float4*)(logits + (size_t)n * M_ + (size_t)qbase);
    const int nq = SEG_ / 4;
    for (int q = threadIdx.x; q < nq; q += 512) {
        float4 v = lp[q];
        float vv[4] = {v.x, v.y, v.z, v.w};
        #pragma unroll
        for (int e = 0; e < 4; ++e) {
            unsigned int u = flip_key(vv[e]);
            if ((u >> BIN_SHIFT) >= B) {
                int qq = qbase + q * 4 + e;
                int a = qq / HW_;
                int hw = qq - a * HW_;
                unsigned int m = (unsigned int)(hw * A_ + a);  // score-order index
                unsigned int pos = atomicAdd(&lcnt, 1u);
                if (pos < CAND_CAP)
                    buf[pos] = ((u64)u << 32) | (unsigned int)(~m);
            }
        }
    }
    __syncthreads();
    unsigned int L = (lcnt < CAND_CAP) ? lcnt : CAND_CAP;
    if (threadIdx.x == 0) gbase = atomicAdd(&cnt[n], L);
    __syncthreads();
    u64* cp = cand + (size_t)n * CAND_CAP;
    for (unsigned int i = threadIdx.x; i < L; i += 512) {
        unsigned int pos = gbase + i;
        if (pos < CAND_CAP) cp[pos] = buf[i];
    }
}

// ---------------- K3: per-batch bitonic sort of 4096 (descending) + fused decode of top-2000 ----------------
__global__ __launch_bounds__(1024) void k_sort(const u64* __restrict__ cand,
                                               const unsigned int* __restrict__ cnt,
                                               const float* __restrict__ anchors,
                                               const float* __restrict__ breg,
                                               float4* __restrict__ boxes,
                                               float* __restrict__ scores,
                                               float* __restrict__ areas) {
    __shared__ u64 sm[CAND_CAP];  // 32 KiB
    int n = blockIdx.x;
    unsigned int Cu = cnt[n];
    int C = (Cu < CAND_CAP) ? (int)Cu : CAND_CAP;
    const u64* cp = cand + (size_t)n * CAND_CAP;
    for (int i = threadIdx.x; i < CAND_CAP; i += 1024)
        sm[i] = (i < C) ? cp[i] : 0ull;
    __syncthreads();
    for (int k = 2; k <= CAND_CAP; k <<= 1) {
        for (int j = k >> 1; j > 0; j >>= 1) {
            for (int i = threadIdx.x; i < CAND_CAP; i += 1024) {
                int ixj = i ^ j;
                if (ixj > i) {
                    u64 va = sm[i], vb = sm[ixj];
                    bool desc = ((i & k) == 0);
                    if (desc ? (va < vb) : (va > vb)) { sm[i] = vb; sm[ixj] = va; }
                }
            }
            __syncthreads();
        }
    }
    // fused decode + clip + validity for the top-2000
    for (int i = threadIdx.x; i < K_TOP; i += 1024) {
        u64 kv = sm[i];
        unsigned int u = (unsigned int)(kv >> 32);
        unsigned int m = ~((unsigned int)kv);
        float logit = unflip_key(u);
        int a = (int)(m % 3u);
        int hw = (int)(m / 3u);
        float4 anc = ((const float4*)anchors)[(size_t)n * M_ + m];
        size_t rb = ((size_t)n * 12 + a * 4) * HW_ + hw;
        float dx = breg[rb];
        float dy = breg[rb + (size_t)HW_];
        float dw = breg[rb + (size_t)2 * HW_];
        float dh = breg[rb + (size_t)3 * HW_];
        float score = 1.0f / (1.0f + expf(-logit));
        float w = anc.z - anc.x + 1.0f;
        float h = anc.w - anc.y + 1.0f;
        float cx = anc.x + 0.5f * w;
        float cy = anc.y + 0.5f * h;
        dw = fminf(dw, XCLIP);
        dh = fminf(dh, XCLIP);
        float pcx = dx * w + cx;
        float pcy = dy * h + cy;
        float pw = expf(dw) * w;
        float ph = expf(dh) * h;
        float x1 = pcx - 0.5f * pw;
        float y1 = pcy - 0.5f * ph;
        float x2 = pcx + 0.5f * pw - 1.0f;
        float y2 = pcy + 0.5f * ph - 1.0f;
        x1 = fminf(fmaxf(x1, 0.0f), 1332.0f);
        y1 = fminf(fmaxf(y1, 0.0f), 799.0f);
        x2 = fminf(fmaxf(x2, 0.0f), 1332.0f);
        y2 = fminf(fmaxf(y2, 0.0f), 799.0f);
        float ww = x2 - x1 + 1.0f;
        float hh = y2 - y1 + 1.0f;
        bool keep = (ww >= 0.0f) && (hh >= 0.0f);  // MIN_SIZE = 0
        int g = n * K_TOP + i;
        boxes[g] = make_float4(x1, y1, x2, y2);
        scores[g] = keep ? score : NEG_;
        areas[g] = ww * hh;
    }
}

// ---------------- K5: dense adjacency bitmask: adj[n][i][w] bit b = IoU(i, 64w+b) > thr ----------------
// NOTE: IoU is computed with fully commutative float ops -> matrix is bitwise symmetric.
// k_resolve depends on this (uses rows as columns).
#define JT 512   // j's per block tile (8 u64 words)
#define RT 64    // rows per block tile
__global__ __launch_bounds__(256) void k_edges(const float4* __restrict__ boxes,
                                               const float* __restrict__ areas,
                                               u64* __restrict__ adj) {
    __shared__ float4 jb[JT];
    __shared__ float ja[JT];
    int n = blockIdx.z;
    int r0 = blockIdx.y * RT;
    int j0 = blockIdx.x * JT;
    for (int j = threadIdx.x; j < JT; j += 256) {
        int jj = j0 + j;
        if (jj < K_TOP) {
            jb[j] = boxes[(size_t)n * K_TOP + jj];
            ja[j] = areas[(size_t)n * K_TOP + jj];
        } else {
            jb[j] = make_float4(-1e8f, -1e8f, -1e8f, -1e8f);  // IoU vs anything = 0
            ja[j] = 0.0f;
        }
    }
    __syncthreads();
    int i = r0 + (threadIdx.x >> 2);       // 4 threads per row
    if (i >= K_TOP) return;
    float4 bi = boxes[(size_t)n * K_TOP + i];
    float ai = areas[(size_t)n * K_TOP + i];
    #pragma unroll
    for (int rep = 0; rep < 2; ++rep) {
        int wl = (threadIdx.x & 3) + rep * 4;  // word-in-tile 0..7
        u64 bits = 0;
        int base = wl * 64;
        #pragma unroll 8
        for (int b = 0; b < 64; ++b) {
            float4 bj = jb[base + b];
            float xx1 = fmaxf(bi.x, bj.x);
            float yy1 = fmaxf(bi.y, bj.y);
            float xx2 = fminf(bi.z, bj.z);
            float yy2 = fminf(bi.w, bj.w);
            float inter = fmaxf(xx2 - xx1 + 1.0f, 0.0f) * fmaxf(yy2 - yy1 + 1.0f, 0.0f);
            float iou = inter / (ai + ja[base + b] - inter);
            bits |= ((u64)(iou > NMS_THR_)) << b;
        }
        adj[((size_t)n * NPAD + i) * NW + (j0 >> 6) + wl] = bits;
    }
}

// ---------------- K6: chunked greedy NMS: ballot-Jacobi diag + block-parallel sup-OR ----------------
__global__ __launch_bounds__(256) void k_resolve(const float4* __restrict__ boxes,
                                                 const float* __restrict__ scores,
                                                 const u64* __restrict__ adj,
                                                 float* __restrict__ out) {
    __shared__ u64 rowbuf[2][64 * NWP];     // 2 x 16.9 KiB (padded rows)
    __shared__ u64 sup[NW];                 // suppressed-mask words (shared, not wave0 regs)
    __shared__ u64 part[8][NW];             // partial ORs, 8 groups
    __shared__ float sls[NPAD];             // 8 KiB
    __shared__ unsigned char alive[NPAD];   // 2 KiB (indices >= K_TOP stay 0)
    __shared__ int list[64];                // compacted alive indices of current chunk
    __shared__ int nalS;
    __shared__ unsigned int scanbuf[256];
    int n = blockIdx.x;
    int tid = threadIdx.x;
    const u64* ab = adj + (size_t)n * NPAD * NW;

    for (int i = tid; i < NPAD; i += 256) {
        sls[i] = (i < K_TOP) ? scores[(size_t)n * K_TOP + i] : NEG_;
        alive[i] = 0;
    }
    if (tid < NW) sup[tid] = 0;
    // preload chunk 0 rows
    for (int idx = tid; idx < 64 * NW; idx += 256) {
        int k = idx >> 5, w = idx & 31;
        rowbuf[0][k * NWP + w] = ab[(size_t)k * NW + w];
    }
    __syncthreads();

    for (int c = 0; c < NCHUNK; ++c) {
        int cur = c & 1, nxt = cur ^ 1;
        if (tid < 64) {  // wave 0: resolve chunk c
            int k = tid;
            int gi = c * 64 + k;
            // symmetric adjacency: row gi's word c == column k of the 64x64 diagonal block
            u64 colk = rowbuf[cur][k * NWP + c];
            u64 supc = sup[c];                         // broadcast read
            bool validk = (sls[gi] > VALID_THR_) && !((supc >> k) & 1ull);
            u64 below = (k == 0) ? 0ull : ((1ull << k) - 1ull);
            u64 rel = colk & below;                    // earlier-in-chunk neighbors
            // ballot-Jacobi: well-founded in k -> unique fixed point == greedy result
            bool a = validk;
            u64 am = __ballot(a);
            while (true) {
                bool anew = validk && ((am & rel) == 0ull);
                u64 am2 = __ballot(anew);
                if (am2 == am) { a = anew; break; }
                am = am2;
            }
            alive[gi] = a ? 1 : 0;
            if (a) list[__popcll(am & below)] = k;     // order-preserving compaction
            if (k == 0) nalS = (int)__popcll(am);
        } else if (c < NCHUNK - 1) {
            // waves 1..3: prefetch chunk c+1 rows (paired u64 -> dwordx4 loads)
            const u64* src = ab + (size_t)(c + 1) * 64 * NW;
            for (int idx = tid - 64; idx < 64 * NW / 2; idx += 192) {
                int k = idx >> 4;                      // 16 pairs per row
                int wp = (idx & 15) * 2;
                u64 a0 = src[k * NW + wp];
                u64 a1 = src[k * NW + wp + 1];
                rowbuf[nxt][k * NWP + wp] = a0;
                rowbuf[nxt][k * NWP + wp + 1] = a1;
            }
        }
        __syncthreads();
        // block-parallel sup-OR: 8 groups x 32 words; each thread ~nal/8 independent LDS reads
        {
            int w = tid & 31, g = tid >> 5;
            int nal = nalS;
            u64 acc = 0;
            for (int i = g; i < nal; i += 8)
                acc |= rowbuf[cur][list[i] * NWP + w];
            part[g][w] = acc;
        }
        __syncthreads();
        if (tid < NW) {
            u64 s = sup[tid];
            #pragma unroll
            for (int g2 = 0; g2 < 8; ++g2) s |= part[g2][tid];
            sup[tid] = s;
        }
        __syncthreads();
    }

    // --- order-preserving compaction of survivors -> output rows ---
    // i0 covers [0,2048): all arrays are NPAD-sized and alive[>=K_TOP]==0 (R3 lesson).
    int i0 = tid * 8;
    unsigned int c2 = 0;
    for (int i = i0; i < i0 + 8; ++i) c2 += alive[i];
    scanbuf[tid] = c2;
    __syncthreads();
    for (int off = 1; off < 256; off <<= 1) {
        unsigned int v = scanbuf[tid];
        unsigned int addv = (tid >= off) ? scanbuf[tid - off] : 0u;
        __syncthreads();
        scanbuf[tid] = v + addv;
        __syncthreads();
    }
    unsigned int r = scanbuf[tid] - c2;
    unsigned int total = scanbuf[255];
    float* op = out + (size_t)n * POST_N * 5;
    const float4* bb = boxes + (size_t)n * K_TOP;
    for (int i = i0; i < i0 + 8; ++i) {
        if (alive[i]) {
            if (r < POST_N) {
                float4 b = bb[i];
                op[r * 5 + 0] = b.x;
                op[r * 5 + 1] = b.y;
                op[r * 5 + 2] = b.z;
                op[r * 5 + 3] = b.w;
                op[r * 5 + 4] = sls[i];
            }
            r++;
        }
    }
    unsigned int S = (total > POST_N) ? POST_N : total;
    for (unsigned int q = S + tid; q < POST_N; q += 256) {
        op[q * 5 + 0] = 0.0f;
        op[q * 5 + 1] = 0.0f;
        op[q * 5 + 2] = 0.0f;
        op[q * 5 + 3] = 0.0f;
        op[q * 5 + 4] = 0.0f;
    }
}

extern "C" void kernel_launch(void* const* d_in, const int* in_sizes, int n_in,
                              void* d_out, int out_size, void* d_ws, size_t ws_size,
                              hipStream_t stream) {
    const float* anchors = (const float*)d_in[0];
    const float* logits  = (const float*)d_in[1];
    const float* breg    = (const float*)d_in[2];
    float* out = (float*)d_out;
    char* ws = (char*)d_ws;

    // ws layout (bytes) — adj ALIASES ghist+cand (both dead before k_edges writes adj):
    // [0, 32)               cnt    : u32[8]              (zeroed each launch)
    // [64, 96)              thresh : u32[8]              (written by k_scan)
    // [128, 2097280)        ghist  : u16[8][HBLK=32][4096]   \ dead after k_scan / k_sort
    // [2097280, 2359424)    cand   : u64[8][4096]            /
    // [128, 4194432)        adj    : u64[8][2048][32]    (written by k_edges after k_sort)
    // [4194432, 4450432)    boxes  : float4[8][2000]
    // [4450432, 4514432)    scores : f32[8][2000]
    // [4514432, 4578432)    areas  : f32[8][2000]
    unsigned int* cnt     = (unsigned int*)(ws);
    unsigned int* thresh  = (unsigned int*)(ws + 64);
    unsigned short* ghist = (unsigned short*)(ws + 128);
    u64* cand             = (u64*)(ws + 2097280);
    u64* adj              = (u64*)(ws + 128);
    float4* boxes         = (float4*)(ws + 4194432);
    float* scores         = (float*)(ws + 4450432);
    float* areas          = (float*)(ws + 4514432);

    hipMemsetAsync(ws, 0, 96, stream);

    k_hist<<<dim3(HBLK, 8), 512, 0, stream>>>(logits, ghist);
    k_scan<<<8, 256, 0, stream>>>(ghist, thresh);
    k_compact<<<dim3(HBLK, 8), 512, 0, stream>>>(logits, thresh, cnt, cand);
    k_sort<<<8, 1024, 0, stream>>>(cand, cnt, anchors, breg, boxes, scores, areas);
    k_edges<<<dim3(NPAD / JT, NPAD / RT, 8), 256, 0, stream>>>(boxes, areas, adj);
    k_resolve<<<8, 256, 0, stream>>>(boxes, scores, adj, out);
}

// Round 8
// 326.307 us; speedup vs baseline: 1.6334x; 1.0031x over previous
//
#include <hip/hip_runtime.h>
#include <stdint.h>

#define N_BATCH 8
#define A_ 3
#define H_ 336
#define W_ 336
#define HW_ (H_*W_)        // 112896
#define M_ (A_*HW_)        // 338688
#define K_TOP 2000
#define POST_N 1000
#define NMS_THR_ 0.7f
#define NEG_ (-1e9f)
#define VALID_THR_ (-5e8f)
#define CAND_CAP 4096
#define NBINS 4096
#define BIN_SHIFT 20       // top 12 bits: sign+exp+3 mantissa
#define HBLK 32            // histogram/compact blocks per batch (256 blocks total)
#define SEG_ (M_/HBLK)     // 10584
#define XCLIP 4.135166556742356f  // log(1000/16)

#define NPAD 2048          // boxes padded to 32 chunks of 64
#define NW 32              // u64 words per adjacency row
#define NWP 33             // padded row stride in LDS (keeps diag reads 4-way, not 32-way)
#define NCHUNK 32
#define RING 4             // ring slots (must divide slot reuse logic: chunk c -> slot c&3)

typedef unsigned long long u64;

__device__ __forceinline__ unsigned int flip_key(float x) {
    unsigned int u = __float_as_uint(x);
    return (u & 0x80000000u) ? ~u : (u | 0x80000000u);
}
__device__ __forceinline__ float unflip_key(unsigned int k) {
    unsigned int u = (k & 0x80000000u) ? (k & 0x7fffffffu) : ~k;
    return __uint_as_float(u);
}

// ---------------- K1: per-block LDS histogram -> private u16 sub-hist (no global atomics) ----------------
__global__ __launch_bounds__(512) void k_hist(const float* __restrict__ logits,
                                              unsigned short* __restrict__ ghist) {
    __shared__ unsigned int h[NBINS];  // 16 KiB
    int n = blockIdx.y, b = blockIdx.x;
    for (int i = threadIdx.x; i < NBINS; i += 512) h[i] = 0;
    __syncthreads();
    const float4* lp = (const float4*)(logits + (size_t)n * M_ + (size_t)b * SEG_);
    const int nq = SEG_ / 4;                 // 2646
    for (int q = threadIdx.x; q < nq; q += 512) {
        float4 v = lp[q];
        atomicAdd(&h[flip_key(v.x) >> BIN_SHIFT], 1u);
        atomicAdd(&h[flip_key(v.y) >> BIN_SHIFT], 1u);
        atomicAdd(&h[flip_key(v.z) >> BIN_SHIFT], 1u);
        atomicAdd(&h[flip_key(v.w) >> BIN_SHIFT], 1u);
    }
    __syncthreads();
    unsigned short* gp = ghist + ((size_t)n * HBLK + b) * NBINS;
    for (int i = threadIdx.x; i < NBINS; i += 512) gp[i] = (unsigned short)h[i];
}

// ---------------- K1b: sum sub-hists, find threshold bin B per batch ----------------
__global__ __launch_bounds__(256) void k_scan(const unsigned short* __restrict__ ghist,
                                              unsigned int* __restrict__ thresh) {
    int n = blockIdx.x;
    int t = threadIdx.x;
    __shared__ unsigned int binsum[NBINS];
    __shared__ unsigned int part[256];
    __shared__ unsigned int scanb[256];
    const unsigned short* base = ghist + (size_t)n * HBLK * NBINS;
    for (int i = t; i < NBINS; i += 256) {
        unsigned int s = 0;
        #pragma unroll 8
        for (int b = 0; b < HBLK; ++b) s += base[(size_t)b * NBINS + i];
        binsum[i] = s;
    }
    __syncthreads();
    // chunk t covers bins [NBINS-16*(t+1), NBINS-16*t) — descending chunks
    int hi = NBINS - 16 * t;
    int lo = hi - 16;
    unsigned int s = 0;
    for (int b = lo; b < hi; ++b) s += binsum[b];
    part[t] = s;
    scanb[t] = s;
    __syncthreads();
    for (int off = 1; off < 256; off <<= 1) {
        unsigned int v = scanb[t];
        unsigned int addv = (t >= off) ? scanb[t - off] : 0u;
        __syncthreads();
        scanb[t] = v + addv;
        __syncthreads();
    }
    unsigned int incl = scanb[t];
    unsigned int prefix = incl - part[t];
    if (prefix < K_TOP && incl >= K_TOP) {
        unsigned int acc = prefix;
        for (int b = hi - 1; b >= lo; --b) {
            unsigned int c = binsum[b];
            if (acc + c >= K_TOP) {
                thresh[n] = (unsigned int)b;
                break;
            }
            acc += c;
        }
    }
}

// ---------------- K2: compact candidates via LDS buffer + 1 global atomic per block ----------------
__global__ __launch_bounds__(512) void k_compact(const float* __restrict__ logits,
                                                 const unsigned int* __restrict__ thresh,
                                                 unsigned int* __restrict__ cnt,
                                                 u64* __restrict__ cand) {
    __shared__ u64 buf[CAND_CAP];  // 32 KiB
    __shared__ unsigned int lcnt;
    __shared__ unsigned int gbase;
    int n = blockIdx.y, b = blockIdx.x;
    unsigned int B = thresh[n];
    if (threadIdx.x == 0) lcnt = 0;
    __syncthreads();
    const int qbase = b * SEG_;
    const float4* lp = (const float4*)(logits + (size_t)n * M_ + (size_t)qbase);
    const int nq = SEG_ / 4;
    for (int q = threadIdx.x; q < nq; q += 512) {
        float4 v = lp[q];
        float vv[4] = {v.x, v.y, v.z, v.w};
        #pragma unroll
        for (int e = 0; e < 4; ++e) {
            unsigned int u = flip_key(vv[e]);
            if ((u >> BIN_SHIFT) >= B) {
                int qq = qbase + q * 4 + e;
                int a = qq / HW_;
                int hw = qq - a * HW_;
                unsigned int m = (unsigned int)(hw * A_ + a);  // score-order index
                unsigned int pos = atomicAdd(&lcnt, 1u);
                if (pos < CAND_CAP)
                    buf[pos] = ((u64)u << 32) | (unsigned int)(~m);
            }
        }
    }
    __syncthreads();
    unsigned int L = (lcnt < CAND_CAP) ? lcnt : CAND_CAP;
    if (threadIdx.x == 0) gbase = atomicAdd(&cnt[n], L);
    __syncthreads();
    u64* cp = cand + (size_t)n * CAND_CAP;
    for (unsigned int i = threadIdx.x; i < L; i += 512) {
        unsigned int pos = gbase + i;
        if (pos < CAND_CAP) cp[pos] = buf[i];
    }
}

// ---------------- K3: per-batch bitonic sort of 4096 (descending) + fused decode of top-2000 ----------------
__global__ __launch_bounds__(1024) void k_sort(const u64* __restrict__ cand,
                                               const unsigned int* __restrict__ cnt,
                                               const float* __restrict__ anchors,
                                               const float* __restrict__ breg,
                                               float4* __restrict__ boxes,
                                               float* __restrict__ scores,
                                               float* __restrict__ areas) {
    __shared__ u64 sm[CAND_CAP];  // 32 KiB
    int n = blockIdx.x;
    unsigned int Cu = cnt[n];
    int C = (Cu < CAND_CAP) ? (int)Cu : CAND_CAP;
    const u64* cp = cand + (size_t)n * CAND_CAP;
    for (int i = threadIdx.x; i < CAND_CAP; i += 1024)
        sm[i] = (i < C) ? cp[i] : 0ull;
    __syncthreads();
    for (int k = 2; k <= CAND_CAP; k <<= 1) {
        for (int j = k >> 1; j > 0; j >>= 1) {
            for (int i = threadIdx.x; i < CAND_CAP; i += 1024) {
                int ixj = i ^ j;
                if (ixj > i) {
                    u64 va = sm[i], vb = sm[ixj];
                    bool desc = ((i & k) == 0);
                    if (desc ? (va < vb) : (va > vb)) { sm[i] = vb; sm[ixj] = va; }
                }
            }
            __syncthreads();
        }
    }
    // fused decode + clip + validity for the top-2000
    for (int i = threadIdx.x; i < K_TOP; i += 1024) {
        u64 kv = sm[i];
        unsigned int u = (unsigned int)(kv >> 32);
        unsigned int m = ~((unsigned int)kv);
        float logit = unflip_key(u);
        int a = (int)(m % 3u);
        int hw = (int)(m / 3u);
        float4 anc = ((const float4*)anchors)[(size_t)n * M_ + m];
        size_t rb = ((size_t)n * 12 + a * 4) * HW_ + hw;
        float dx = breg[rb];
        float dy = breg[rb + (size_t)HW_];
        float dw = breg[rb + (size_t)2 * HW_];
        float dh = breg[rb + (size_t)3 * HW_];
        float score = 1.0f / (1.0f + expf(-logit));
        float w = anc.z - anc.x + 1.0f;
        float h = anc.w - anc.y + 1.0f;
        float cx = anc.x + 0.5f * w;
        float cy = anc.y + 0.5f * h;
        dw = fminf(dw, XCLIP);
        dh = fminf(dh, XCLIP);
        float pcx = dx * w + cx;
        float pcy = dy * h + cy;
        float pw = expf(dw) * w;
        float ph = expf(dh) * h;
        float x1 = pcx - 0.5f * pw;
        float y1 = pcy - 0.5f * ph;
        float x2 = pcx + 0.5f * pw - 1.0f;
        float y2 = pcy + 0.5f * ph - 1.0f;
        x1 = fminf(fmaxf(x1, 0.0f), 1332.0f);
        y1 = fminf(fmaxf(y1, 0.0f), 799.0f);
        x2 = fminf(fmaxf(x2, 0.0f), 1332.0f);
        y2 = fminf(fmaxf(y2, 0.0f), 799.0f);
        float ww = x2 - x1 + 1.0f;
        float hh = y2 - y1 + 1.0f;
        bool keep = (ww >= 0.0f) && (hh >= 0.0f);  // MIN_SIZE = 0
        int g = n * K_TOP + i;
        boxes[g] = make_float4(x1, y1, x2, y2);
        scores[g] = keep ? score : NEG_;
        areas[g] = ww * hh;
    }
}

// ---------------- K5: dense adjacency bitmask: adj[n][i][w] bit b = IoU(i, 64w+b) > thr ----------------
// NOTE: IoU is computed with fully commutative float ops -> matrix is bitwise symmetric.
// k_resolve depends on this (uses rows as columns).
#define JT 512   // j's per block tile (8 u64 words)
#define RT 64    // rows per block tile
__global__ __launch_bounds__(256) void k_edges(const float4* __restrict__ boxes,
                                               const float* __restrict__ areas,
                                               u64* __restrict__ adj) {
    __shared__ float4 jb[JT];
    __shared__ float ja[JT];
    int n = blockIdx.z;
    int r0 = blockIdx.y * RT;
    int j0 = blockIdx.x * JT;
    for (int j = threadIdx.x; j < JT; j += 256) {
        int jj = j0 + j;
        if (jj < K_TOP) {
            jb[j] = boxes[(size_t)n * K_TOP + jj];
            ja[j] = areas[(size_t)n * K_TOP + jj];
        } else {
            jb[j] = make_float4(-1e8f, -1e8f, -1e8f, -1e8f);  // IoU vs anything = 0
            ja[j] = 0.0f;
        }
    }
    __syncthreads();
    int i = r0 + (threadIdx.x >> 2);       // 4 threads per row
    if (i >= K_TOP) return;
    float4 bi = boxes[(size_t)n * K_TOP + i];
    float ai = areas[(size_t)n * K_TOP + i];
    #pragma unroll
    for (int rep = 0; rep < 2; ++rep) {
        int wl = (threadIdx.x & 3) + rep * 4;  // word-in-tile 0..7
        u64 bits = 0;
        int base = wl * 64;
        #pragma unroll 8
        for (int b = 0; b < 64; ++b) {
            float4 bj = jb[base + b];
            float xx1 = fmaxf(bi.x, bj.x);
            float yy1 = fmaxf(bi.y, bj.y);
            float xx2 = fminf(bi.z, bj.z);
            float yy2 = fminf(bi.w, bj.w);
            float inter = fmaxf(xx2 - xx1 + 1.0f, 0.0f) * fmaxf(yy2 - yy1 + 1.0f, 0.0f);
            float iou = inter / (ai + ja[base + b] - inter);
            bits |= ((u64)(iou > NMS_THR_)) << b;
        }
        adj[((size_t)n * NPAD + i) * NW + (j0 >> 6) + wl] = bits;
    }
}

// ---------------- K6: wave-specialized greedy NMS: resolver wave + prefetcher waves, NO per-chunk barriers ----------------
// Barrier-drain pathology: __syncthreads forces vmcnt(0) drain per chunk (m97 stall). Instead:
// wave 0 resolves chunks sequentially; waves 1-3 stream chunks into a 4-slot LDS ring,
// synchronized via LDS acquire/release flags (lgkmcnt-only, per-wave drain).
__global__ __launch_bounds__(256) void k_resolve(const float4* __restrict__ boxes,
                                                 const float* __restrict__ scores,
                                                 const u64* __restrict__ adj,
                                                 float* __restrict__ out) {
    __shared__ u64 ring[RING][64 * NWP];    // 4 x 16.9 KiB = 67.6 KiB
    __shared__ float sls[NPAD];             // 8 KiB
    __shared__ unsigned char alive[NPAD];   // 2 KiB (indices >= K_TOP stay 0)
    __shared__ int list[64];                // alive indices of current chunk (resolver-wave private)
    __shared__ int ready[RING];             // slot s holds chunk c when ready[s]==c+1
    __shared__ int progress;                // # chunks fully resolved
    __shared__ unsigned int scanbuf[256];
    int n = blockIdx.x;
    int tid = threadIdx.x;
    int wave = tid >> 6, lane = tid & 63;
    const u64* ab = adj + (size_t)n * NPAD * NW;

    for (int i = tid; i < NPAD; i += 256) {
        sls[i] = (i < K_TOP) ? scores[(size_t)n * K_TOP + i] : NEG_;
        alive[i] = 0;
    }
    if (tid < RING) ready[tid] = 0;
    if (tid == 0) progress = 0;
    __syncthreads();  // init visible to all waves (the ONLY barrier before the epilogue)

    if (wave == 0) {
        // ---- resolver ----
        u64 supreg = 0;  // lane w (w<32) holds suppressed-mask word w
        for (int c = 0; c < NCHUNK; ++c) {
            int slot = c & (RING - 1);
            while (__hip_atomic_load(&ready[slot], __ATOMIC_ACQUIRE,
                                     __HIP_MEMORY_SCOPE_WORKGROUP) != c + 1)
                __builtin_amdgcn_s_sleep(1);
            int k = lane;
            int gi = c * 64 + k;
            // symmetric adjacency: row gi word c == column k of the diag block
            u64 colk = ring[slot][k * NWP + c];
            u64 supc = __shfl(supreg, c, 64);
            bool validk = (sls[gi] > VALID_THR_) && !((supc >> k) & 1ull);
            u64 below = (k == 0) ? 0ull : ((1ull << k) - 1ull);
            u64 rel = colk & below;
            // ballot-Jacobi: well-founded in k -> unique fixed point == greedy result
            bool a = validk;
            u64 am = __ballot(a);
            while (true) {
                bool anew = validk && ((am & rel) == 0ull);
                u64 am2 = __ballot(anew);
                if (am2 == am) { a = anew; break; }
                am = am2;
            }
            alive[gi] = a ? 1 : 0;
            if (a) list[__popcll(am & below)] = k;
            int nal = (int)__popcll(am);
            // sup-OR inside resolver wave: lane = half*32 + w; ~nal/2 independent LDS reads per lane
            int w = lane & 31, half = lane >> 5;
            u64 acc = 0;
            for (int i = half; i < nal; i += 2)
                acc |= ring[slot][list[i] * NWP + w];
            acc |= __shfl_down(acc, 32);    // fold half 1 into half 0
            if (lane < 32) supreg |= acc;
            if (lane == 0)
                __hip_atomic_store(&progress, c + 1, __ATOMIC_RELEASE,
                                   __HIP_MEMORY_SCOPE_WORKGROUP);
        }
    } else {
        // ---- prefetchers: wave v handles chunks v-1, v+2, v+5, ... ----
        for (int c = wave - 1; c < NCHUNK; c += 3) {
            int slot = c & (RING - 1);
            // slot free once chunk c-4 consumed: progress >= c-3
            while (__hip_atomic_load(&progress, __ATOMIC_ACQUIRE,
                                     __HIP_MEMORY_SCOPE_WORKGROUP) < c - 3)
                __builtin_amdgcn_s_sleep(1);
            const u64* src = ab + (size_t)c * 64 * NW;
            for (int idx = lane; idx < 64 * NW / 2; idx += 64) {  // 16 iters x 16B, coalesced
                int k2 = idx >> 4;
                int wp = (idx & 15) * 2;
                u64 a0 = src[k2 * NW + wp];
                u64 a1 = src[k2 * NW + wp + 1];
                ring[slot][k2 * NWP + wp] = a0;
                ring[slot][k2 * NWP + wp + 1] = a1;
            }
            // release store drains this wave's ds_writes (lgkmcnt), then publishes
            if (lane == 0)
                __hip_atomic_store(&ready[slot], c + 1, __ATOMIC_RELEASE,
                                   __HIP_MEMORY_SCOPE_WORKGROUP);
        }
    }
    __syncthreads();

    // --- order-preserving compaction of survivors -> output rows ---
    // i0 covers [0,2048): all arrays are NPAD-sized and alive[>=K_TOP]==0 (R3 lesson).
    int i0 = tid * 8;
    unsigned int c2 = 0;
    for (int i = i0; i < i0 + 8; ++i) c2 += alive[i];
    scanbuf[tid] = c2;
    __syncthreads();
    for (int off = 1; off < 256; off <<= 1) {
        unsigned int v = scanbuf[tid];
        unsigned int addv = (tid >= off) ? scanbuf[tid - off] : 0u;
        __syncthreads();
        scanbuf[tid] = v + addv;
        __syncthreads();
    }
    unsigned int r = scanbuf[tid] - c2;
    unsigned int total = scanbuf[255];
    float* op = out + (size_t)n * POST_N * 5;
    const float4* bb = boxes + (size_t)n * K_TOP;
    for (int i = i0; i < i0 + 8; ++i) {
        if (alive[i]) {
            if (r < POST_N) {
                float4 b = bb[i];
                op[r * 5 + 0] = b.x;
                op[r * 5 + 1] = b.y;
                op[r * 5 + 2] = b.z;
                op[r * 5 + 3] = b.w;
                op[r * 5 + 4] = sls[i];
            }
            r++;
        }
    }
    unsigned int S = (total > POST_N) ? POST_N : total;
    for (unsigned int q = S + tid; q < POST_N; q += 256) {
        op[q * 5 + 0] = 0.0f;
        op[q * 5 + 1] = 0.0f;
        op[q * 5 + 2] = 0.0f;
        op[q * 5 + 3] = 0.0f;
        op[q * 5 + 4] = 0.0f;
    }
}

extern "C" void kernel_launch(void* const* d_in, const int* in_sizes, int n_in,
                              void* d_out, int out_size, void* d_ws, size_t ws_size,
                              hipStream_t stream) {
    const float* anchors = (const float*)d_in[0];
    const float* logits  = (const float*)d_in[1];
    const float* breg    = (const float*)d_in[2];
    float* out = (float*)d_out;
    char* ws = (char*)d_ws;

    // ws layout (bytes) — adj ALIASES ghist+cand (both dead before k_edges writes adj):
    // [0, 32)               cnt    : u32[8]              (zeroed each launch)
    // [64, 96)              thresh : u32[8]              (written by k_scan)
    // [128, 2097280)        ghist  : u16[8][HBLK=32][4096]   \ dead after k_scan / k_sort
    // [2097280, 2359424)    cand   : u64[8][4096]            /
    // [128, 4194432)        adj    : u64[8][2048][32]    (written by k_edges after k_sort)
    // [4194432, 4450432)    boxes  : float4[8][2000]
    // [4450432, 4514432)    scores : f32[8][2000]
    // [4514432, 4578432)    areas  : f32[8][2000]
    unsigned int* cnt     = (unsigned int*)(ws);
    unsigned int* thresh  = (unsigned int*)(ws + 64);
    unsigned short* ghist = (unsigned short*)(ws + 128);
    u64* cand             = (u64*)(ws + 2097280);
    u64* adj              = (u64*)(ws + 128);
    float4* boxes         = (float4*)(ws + 4194432);
    float* scores         = (float*)(ws + 4450432);
    float* areas          = (float*)(ws + 4514432);

    hipMemsetAsync(ws, 0, 96, stream);

    k_hist<<<dim3(HBLK, 8), 512, 0, stream>>>(logits, ghist);
    k_scan<<<8, 256, 0, stream>>>(ghist, thresh);
    k_compact<<<dim3(HBLK, 8), 512, 0, stream>>>(logits, thresh, cnt, cand);
    k_sort<<<8, 1024, 0, stream>>>(cand, cnt, anchors, breg, boxes, scores, areas);
    k_edges<<<dim3(NPAD / JT, NPAD / RT, 8), 256, 0, stream>>>(boxes, areas, adj);
    k_resolve<<<8, 256, 0, stream>>>(boxes, scores, adj, out);
}

// Round 9
// 274.671 us; speedup vs baseline: 1.9405x; 1.1880x over previous
//
#include <hip/hip_runtime.h>
#include <stdint.h>

#define N_BATCH 8
#define A_ 3
#define H_ 336
#define W_ 336
#define HW_ (H_*W_)        // 112896
#define M_ (A_*HW_)        // 338688
#define K_TOP 2000
#define POST_N 1000
#define NMS_THR_ 0.7f
#define NEG_ (-1e9f)
#define VALID_THR_ (-5e8f)
#define CAND_CAP 4096
#define NBINS 4096
#define BIN_SHIFT 20       // top 12 bits: sign+exp+3 mantissa
#define HBLK 32            // histogram/compact blocks per batch (256 blocks total)
#define SEG_ (M_/HBLK)     // 10584
#define XCLIP 4.135166556742356f  // log(1000/16)

#define NPAD 2048          // boxes padded to 32 chunks of 64
#define NW 32              // u64 words per adjacency row
#define NWP 33             // padded row stride in LDS (keeps diag reads 4-way, not 32-way)
#define NCHUNK 32
#define RING 4             // ring slots (chunk c -> slot c&3)

typedef unsigned long long u64;

__device__ __forceinline__ unsigned int flip_key(float x) {
    unsigned int u = __float_as_uint(x);
    return (u & 0x80000000u) ? ~u : (u | 0x80000000u);
}
__device__ __forceinline__ float unflip_key(unsigned int k) {
    unsigned int u = (k & 0x80000000u) ? (k & 0x7fffffffu) : ~k;
    return __uint_as_float(u);
}

// ---------------- K1: per-block LDS histogram -> private u16 sub-hist (no global atomics) ----------------
__global__ __launch_bounds__(512) void k_hist(const float* __restrict__ logits,
                                              unsigned short* __restrict__ ghist) {
    __shared__ unsigned int h[NBINS];  // 16 KiB
    int n = blockIdx.y, b = blockIdx.x;
    for (int i = threadIdx.x; i < NBINS; i += 512) h[i] = 0;
    __syncthreads();
    const float4* lp = (const float4*)(logits + (size_t)n * M_ + (size_t)b * SEG_);
    const int nq = SEG_ / 4;                 // 2646
    for (int q = threadIdx.x; q < nq; q += 512) {
        float4 v = lp[q];
        atomicAdd(&h[flip_key(v.x) >> BIN_SHIFT], 1u);
        atomicAdd(&h[flip_key(v.y) >> BIN_SHIFT], 1u);
        atomicAdd(&h[flip_key(v.z) >> BIN_SHIFT], 1u);
        atomicAdd(&h[flip_key(v.w) >> BIN_SHIFT], 1u);
    }
    __syncthreads();
    unsigned short* gp = ghist + ((size_t)n * HBLK + b) * NBINS;
    for (int i = threadIdx.x; i < NBINS; i += 512) gp[i] = (unsigned short)h[i];
}

// ---------------- K1b: sum sub-hists, find threshold bin B per batch ----------------
__global__ __launch_bounds__(256) void k_scan(const unsigned short* __restrict__ ghist,
                                              unsigned int* __restrict__ thresh) {
    int n = blockIdx.x;
    int t = threadIdx.x;
    __shared__ unsigned int binsum[NBINS];
    __shared__ unsigned int part[256];
    __shared__ unsigned int scanb[256];
    const unsigned short* base = ghist + (size_t)n * HBLK * NBINS;
    for (int i = t; i < NBINS; i += 256) {
        unsigned int s = 0;
        #pragma unroll 8
        for (int b = 0; b < HBLK; ++b) s += base[(size_t)b * NBINS + i];
        binsum[i] = s;
    }
    __syncthreads();
    // chunk t covers bins [NBINS-16*(t+1), NBINS-16*t) — descending chunks
    int hi = NBINS - 16 * t;
    int lo = hi - 16;
    unsigned int s = 0;
    for (int b = lo; b < hi; ++b) s += binsum[b];
    part[t] = s;
    scanb[t] = s;
    __syncthreads();
    for (int off = 1; off < 256; off <<= 1) {
        unsigned int v = scanb[t];
        unsigned int addv = (t >= off) ? scanb[t - off] : 0u;
        __syncthreads();
        scanb[t] = v + addv;
        __syncthreads();
    }
    unsigned int incl = scanb[t];
    unsigned int prefix = incl - part[t];
    if (prefix < K_TOP && incl >= K_TOP) {
        unsigned int acc = prefix;
        for (int b = hi - 1; b >= lo; --b) {
            unsigned int c = binsum[b];
            if (acc + c >= K_TOP) {
                thresh[n] = (unsigned int)b;
                break;
            }
            acc += c;
        }
    }
}

// ---------------- K2: compact candidates via LDS buffer + 1 global atomic per block ----------------
__global__ __launch_bounds__(512) void k_compact(const float* __restrict__ logits,
                                                 const unsigned int* __restrict__ thresh,
                                                 unsigned int* __restrict__ cnt,
                                                 u64* __restrict__ cand) {
    __shared__ u64 buf[CAND_CAP];  // 32 KiB
    __shared__ unsigned int lcnt;
    __shared__ unsigned int gbase;
    int n = blockIdx.y, b = blockIdx.x;
    unsigned int B = thresh[n];
    if (threadIdx.x == 0) lcnt = 0;
    __syncthreads();
    const int qbase = b * SEG_;
    const float4* lp = (const float4*)(logits + (size_t)n * M_ + (size_t)qbase);
    const int nq = SEG_ / 4;
    for (int q = threadIdx.x; q < nq; q += 512) {
        float4 v = lp[q];
        float vv[4] = {v.x, v.y, v.z, v.w};
        #pragma unroll
        for (int e = 0; e < 4; ++e) {
            unsigned int u = flip_key(vv[e]);
            if ((u >> BIN_SHIFT) >= B) {
                int qq = qbase + q * 4 + e;
                int a = qq / HW_;
                int hw = qq - a * HW_;
                unsigned int m = (unsigned int)(hw * A_ + a);  // score-order index
                unsigned int pos = atomicAdd(&lcnt, 1u);
                if (pos < CAND_CAP)
                    buf[pos] = ((u64)u << 32) | (unsigned int)(~m);
            }
        }
    }
    __syncthreads();
    unsigned int L = (lcnt < CAND_CAP) ? lcnt : CAND_CAP;
    if (threadIdx.x == 0) gbase = atomicAdd(&cnt[n], L);
    __syncthreads();
    u64* cp = cand + (size_t)n * CAND_CAP;
    for (unsigned int i = threadIdx.x; i < L; i += 512) {
        unsigned int pos = gbase + i;
        if (pos < CAND_CAP) cp[pos] = buf[i];
    }
}

// ---------------- K3: rank-by-counting (replaces bitonic sort) + fused decode ----------------
// Keys are unique -> rank(i) = #{j: key_j > key_i} is a permutation; rank < K_TOP
// candidates ARE the sorted top-2000 (desc, ties by smaller m — matches lax.top_k).
// Whole wave reads same keys[j] -> LDS broadcast, conflict-free. No barriers in hot loop.
__global__ __launch_bounds__(512) void k_rank(const u64* __restrict__ cand,
                                              const unsigned int* __restrict__ cnt,
                                              const float* __restrict__ anchors,
                                              const float* __restrict__ breg,
                                              float4* __restrict__ boxes,
                                              float* __restrict__ scores,
                                              float* __restrict__ areas) {
    __shared__ u64 keys[CAND_CAP];          // 32 KiB
    __shared__ unsigned short psum[512];
    int n = blockIdx.y;
    int bx = blockIdx.x;
    unsigned int Cu = cnt[n];
    int C = (Cu < CAND_CAP) ? (int)Cu : CAND_CAP;
    const u64* cp = cand + (size_t)n * CAND_CAP;
    for (int i = threadIdx.x; i < C; i += 512) keys[i] = cp[i];
    __syncthreads();
    int t = threadIdx.x;
    int ci = bx * 256 + (t & 255);
    int half = t >> 8;                       // wave-uniform (waves 0-3: 0, waves 4-7: 1)
    unsigned int r = 0;
    u64 ki = 0;
    if (ci < C) {
        ki = keys[ci];
        int j = half;
        for (; j + 6 < C; j += 8) {          // 4 accumulations/iter, independent cmps
            r += (keys[j] > ki);
            r += (keys[j + 2] > ki);
            r += (keys[j + 4] > ki);
            r += (keys[j + 6] > ki);
        }
        for (; j < C; j += 2) r += (keys[j] > ki);
    }
    psum[t] = (unsigned short)r;
    __syncthreads();
    if (t < 256 && ci < C) {
        unsigned int rank = (unsigned int)psum[t] + (unsigned int)psum[t + 256];
        if (rank < K_TOP) {
            unsigned int u = (unsigned int)(ki >> 32);
            unsigned int m = ~((unsigned int)ki);
            float logit = unflip_key(u);
            int a = (int)(m % 3u);
            int hw = (int)(m / 3u);
            float4 anc = ((const float4*)anchors)[(size_t)n * M_ + m];
            size_t rb = ((size_t)n * 12 + a * 4) * HW_ + hw;
            float dx = breg[rb];
            float dy = breg[rb + (size_t)HW_];
            float dw = breg[rb + (size_t)2 * HW_];
            float dh = breg[rb + (size_t)3 * HW_];
            float score = 1.0f / (1.0f + expf(-logit));
            float w = anc.z - anc.x + 1.0f;
            float h = anc.w - anc.y + 1.0f;
            float cx = anc.x + 0.5f * w;
            float cy = anc.y + 0.5f * h;
            dw = fminf(dw, XCLIP);
            dh = fminf(dh, XCLIP);
            float pcx = dx * w + cx;
            float pcy = dy * h + cy;
            float pw = expf(dw) * w;
            float ph = expf(dh) * h;
            float x1 = pcx - 0.5f * pw;
            float y1 = pcy - 0.5f * ph;
            float x2 = pcx + 0.5f * pw - 1.0f;
            float y2 = pcy + 0.5f * ph - 1.0f;
            x1 = fminf(fmaxf(x1, 0.0f), 1332.0f);
            y1 = fminf(fmaxf(y1, 0.0f), 799.0f);
            x2 = fminf(fmaxf(x2, 0.0f), 1332.0f);
            y2 = fminf(fmaxf(y2, 0.0f), 799.0f);
            float ww = x2 - x1 + 1.0f;
            float hh = y2 - y1 + 1.0f;
            bool keep = (ww >= 0.0f) && (hh >= 0.0f);  // MIN_SIZE = 0
            int g = n * K_TOP + (int)rank;
            boxes[g] = make_float4(x1, y1, x2, y2);
            scores[g] = keep ? score : NEG_;
            areas[g] = ww * hh;
        }
    }
}

// ---------------- K5: dense adjacency bitmask: adj[n][i][w] bit b = IoU(i, 64w+b) > thr ----------------
// NOTE: IoU is computed with fully commutative float ops -> matrix is bitwise symmetric.
// k_resolve depends on this (uses rows as columns).
#define JT 512   // j's per block tile (8 u64 words)
#define RT 64    // rows per block tile
__global__ __launch_bounds__(256) void k_edges(const float4* __restrict__ boxes,
                                               const float* __restrict__ areas,
                                               u64* __restrict__ adj) {
    __shared__ float4 jb[JT];
    __shared__ float ja[JT];
    int n = blockIdx.z;
    int r0 = blockIdx.y * RT;
    int j0 = blockIdx.x * JT;
    for (int j = threadIdx.x; j < JT; j += 256) {
        int jj = j0 + j;
        if (jj < K_TOP) {
            jb[j] = boxes[(size_t)n * K_TOP + jj];
            ja[j] = areas[(size_t)n * K_TOP + jj];
        } else {
            jb[j] = make_float4(-1e8f, -1e8f, -1e8f, -1e8f);  // IoU vs anything = 0
            ja[j] = 0.0f;
        }
    }
    __syncthreads();
    int i = r0 + (threadIdx.x >> 2);       // 4 threads per row
    if (i >= K_TOP) return;
    float4 bi = boxes[(size_t)n * K_TOP + i];
    float ai = areas[(size_t)n * K_TOP + i];
    #pragma unroll
    for (int rep = 0; rep < 2; ++rep) {
        int wl = (threadIdx.x & 3) + rep * 4;  // word-in-tile 0..7
        u64 bits = 0;
        int base = wl * 64;
        #pragma unroll 8
        for (int b = 0; b < 64; ++b) {
            float4 bj = jb[base + b];
            float xx1 = fmaxf(bi.x, bj.x);
            float yy1 = fmaxf(bi.y, bj.y);
            float xx2 = fminf(bi.z, bj.z);
            float yy2 = fminf(bi.w, bj.w);
            float inter = fmaxf(xx2 - xx1 + 1.0f, 0.0f) * fmaxf(yy2 - yy1 + 1.0f, 0.0f);
            float iou = inter / (ai + ja[base + b] - inter);
            bits |= ((u64)(iou > NMS_THR_)) << b;
        }
        adj[((size_t)n * NPAD + i) * NW + (j0 >> 6) + wl] = bits;
    }
}

// ---------------- K6: wave-specialized greedy NMS (resolver wave + prefetcher waves) ----------------
__global__ __launch_bounds__(256) void k_resolve(const float4* __restrict__ boxes,
                                                 const float* __restrict__ scores,
                                                 const u64* __restrict__ adj,
                                                 float* __restrict__ out) {
    __shared__ u64 ring[RING][64 * NWP];    // 4 x 16.9 KiB = 67.6 KiB
    __shared__ float sls[NPAD];             // 8 KiB
    __shared__ unsigned char alive[NPAD];   // 2 KiB (indices >= K_TOP stay 0)
    __shared__ int list[64];                // alive indices of current chunk (resolver-wave private)
    __shared__ int ready[RING];             // slot s holds chunk c when ready[s]==c+1
    __shared__ int progress;                // # chunks fully resolved
    __shared__ unsigned int scanbuf[256];
    int n = blockIdx.x;
    int tid = threadIdx.x;
    int wave = tid >> 6, lane = tid & 63;
    const u64* ab = adj + (size_t)n * NPAD * NW;

    for (int i = tid; i < NPAD; i += 256) {
        sls[i] = (i < K_TOP) ? scores[(size_t)n * K_TOP + i] : NEG_;
        alive[i] = 0;
    }
    if (tid < RING) ready[tid] = 0;
    if (tid == 0) progress = 0;
    __syncthreads();  // init visible to all waves (the ONLY barrier before the epilogue)

    if (wave == 0) {
        // ---- resolver ----
        u64 supreg = 0;  // lane w (w<32) holds suppressed-mask word w
        for (int c = 0; c < NCHUNK; ++c) {
            int slot = c & (RING - 1);
            while (__hip_atomic_load(&ready[slot], __ATOMIC_ACQUIRE,
                                     __HIP_MEMORY_SCOPE_WORKGROUP) != c + 1)
                __builtin_amdgcn_s_sleep(1);
            int k = lane;
            int gi = c * 64 + k;
            // symmetric adjacency: row gi word c == column k of the diag block
            u64 colk = ring[slot][k * NWP + c];
            u64 supc = __shfl(supreg, c, 64);
            bool validk = (sls[gi] > VALID_THR_) && !((supc >> k) & 1ull);
            u64 below = (k == 0) ? 0ull : ((1ull << k) - 1ull);
            u64 rel = colk & below;
            // ballot-Jacobi: well-founded in k -> unique fixed point == greedy result
            bool a = validk;
            u64 am = __ballot(a);
            while (true) {
                bool anew = validk && ((am & rel) == 0ull);
                u64 am2 = __ballot(anew);
                if (am2 == am) { a = anew; break; }
                am = am2;
            }
            alive[gi] = a ? 1 : 0;
            if (a) list[__popcll(am & below)] = k;
            int nal = (int)__popcll(am);
            // sup-OR inside resolver wave: lane = half*32 + w
            int w = lane & 31, half = lane >> 5;
            u64 acc = 0;
            for (int i = half; i < nal; i += 2)
                acc |= ring[slot][list[i] * NWP + w];
            acc |= __shfl_down(acc, 32);    // fold half 1 into half 0
            if (lane < 32) supreg |= acc;
            if (lane == 0)
                __hip_atomic_store(&progress, c + 1, __ATOMIC_RELEASE,
                                   __HIP_MEMORY_SCOPE_WORKGROUP);
        }
    } else {
        // ---- prefetchers: wave v handles chunks v-1, v+2, v+5, ... ----
        for (int c = wave - 1; c < NCHUNK; c += 3) {
            int slot = c & (RING - 1);
            // slot free once chunk c-4 consumed: progress >= c-3
            while (__hip_atomic_load(&progress, __ATOMIC_ACQUIRE,
                                     __HIP_MEMORY_SCOPE_WORKGROUP) < c - 3)
                __builtin_amdgcn_s_sleep(1);
            const u64* src = ab + (size_t)c * 64 * NW;
            for (int idx = lane; idx < 64 * NW / 2; idx += 64) {  // 16 iters x 16B, coalesced
                int k2 = idx >> 4;
                int wp = (idx & 15) * 2;
                u64 a0 = src[k2 * NW + wp];
                u64 a1 = src[k2 * NW + wp + 1];
                ring[slot][k2 * NWP + wp] = a0;
                ring[slot][k2 * NWP + wp + 1] = a1;
            }
            // release store drains this wave's ds_writes (lgkmcnt), then publishes
            if (lane == 0)
                __hip_atomic_store(&ready[slot], c + 1, __ATOMIC_RELEASE,
                                   __HIP_MEMORY_SCOPE_WORKGROUP);
        }
    }
    __syncthreads();

    // --- order-preserving compaction of survivors -> output rows ---
    // i0 covers [0,2048): all arrays are NPAD-sized and alive[>=K_TOP]==0 (R3 lesson).
    int i0 = tid * 8;
    unsigned int c2 = 0;
    for (int i = i0; i < i0 + 8; ++i) c2 += alive[i];
    scanbuf[tid] = c2;
    __syncthreads();
    for (int off = 1; off < 256; off <<= 1) {
        unsigned int v = scanbuf[tid];
        unsigned int addv = (tid >= off) ? scanbuf[tid - off] : 0u;
        __syncthreads();
        scanbuf[tid] = v + addv;
        __syncthreads();
    }
    unsigned int r = scanbuf[tid] - c2;
    unsigned int total = scanbuf[255];
    float* op = out + (size_t)n * POST_N * 5;
    const float4* bb = boxes + (size_t)n * K_TOP;
    for (int i = i0; i < i0 + 8; ++i) {
        if (alive[i]) {
            if (r < POST_N) {
                float4 b = bb[i];
                op[r * 5 + 0] = b.x;
                op[r * 5 + 1] = b.y;
                op[r * 5 + 2] = b.z;
                op[r * 5 + 3] = b.w;
                op[r * 5 + 4] = sls[i];
            }
            r++;
        }
    }
    unsigned int S = (total > POST_N) ? POST_N : total;
    for (unsigned int q = S + tid; q < POST_N; q += 256) {
        op[q * 5 + 0] = 0.0f;
        op[q * 5 + 1] = 0.0f;
        op[q * 5 + 2] = 0.0f;
        op[q * 5 + 3] = 0.0f;
        op[q * 5 + 4] = 0.0f;
    }
}

extern "C" void kernel_launch(void* const* d_in, const int* in_sizes, int n_in,
                              void* d_out, int out_size, void* d_ws, size_t ws_size,
                              hipStream_t stream) {
    const float* anchors = (const float*)d_in[0];
    const float* logits  = (const float*)d_in[1];
    const float* breg    = (const float*)d_in[2];
    float* out = (float*)d_out;
    char* ws = (char*)d_ws;

    // ws layout (bytes) — adj ALIASES ghist+cand (both dead before k_edges writes adj):
    // [0, 32)               cnt    : u32[8]              (zeroed each launch)
    // [64, 96)              thresh : u32[8]              (written by k_scan)
    // [128, 2097280)        ghist  : u16[8][HBLK=32][4096]   \ dead after k_scan / k_rank
    // [2097280, 2359424)    cand   : u64[8][4096]            /
    // [128, 4194432)        adj    : u64[8][2048][32]    (written by k_edges after k_rank)
    // [4194432, 4450432)    boxes  : float4[8][2000]
    // [4450432, 4514432)    scores : f32[8][2000]
    // [4514432, 4578432)    areas  : f32[8][2000]
    unsigned int* cnt     = (unsigned int*)(ws);
    unsigned int* thresh  = (unsigned int*)(ws + 64);
    unsigned short* ghist = (unsigned short*)(ws + 128);
    u64* cand             = (u64*)(ws + 2097280);
    u64* adj              = (u64*)(ws + 128);
    float4* boxes         = (float4*)(ws + 4194432);
    float* scores         = (float*)(ws + 4450432);
    float* areas          = (float*)(ws + 4514432);

    hipMemsetAsync(ws, 0, 96, stream);

    k_hist<<<dim3(HBLK, 8), 512, 0, stream>>>(logits, ghist);
    k_scan<<<8, 256, 0, stream>>>(ghist, thresh);
    k_compact<<<dim3(HBLK, 8), 512, 0, stream>>>(logits, thresh, cnt, cand);
    k_rank<<<dim3(16, 8), 512, 0, stream>>>(cand, cnt, anchors, breg, boxes, scores, areas);
    k_edges<<<dim3(NPAD / JT, NPAD / RT, 8), 256, 0, stream>>>(boxes, areas, adj);
    k_resolve<<<8, 256, 0, stream>>>(boxes, scores, adj, out);
}

// Round 10
// 271.893 us; speedup vs baseline: 1.9603x; 1.0102x over previous
//
#include <hip/hip_runtime.h>
#include <stdint.h>

#define N_BATCH 8
#define A_ 3
#define H_ 336
#define W_ 336
#define HW_ (H_*W_)        // 112896
#define M_ (A_*HW_)        // 338688
#define K_TOP 2000
#define POST_N 1000
#define NMS_THR_ 0.7f
#define NEG_ (-1e9f)
#define VALID_THR_ (-5e8f)
#define CAND_CAP 4096
#define NBINS 4096
#define BIN_SHIFT 20       // top 12 bits: sign+exp+3 mantissa
#define HBLK 32            // histogram/compact blocks per batch (256 blocks total)
#define SEG_ (M_/HBLK)     // 10584
#define XCLIP 4.135166556742356f  // log(1000/16)

#define NPAD 2048          // boxes padded to 32 chunks of 64
#define NW 32              // u64 words per adjacency row (ring UNPADDED: global_load_lds needs contiguity)
#define NCHUNK 32
#define RING 4             // ring slots (chunk c -> slot c&3)

typedef unsigned long long u64;

__device__ __forceinline__ unsigned int flip_key(float x) {
    unsigned int u = __float_as_uint(x);
    return (u & 0x80000000u) ? ~u : (u | 0x80000000u);
}
__device__ __forceinline__ float unflip_key(unsigned int k) {
    unsigned int u = (k & 0x80000000u) ? (k & 0x7fffffffu) : ~k;
    return __uint_as_float(u);
}

// Direct global->LDS DMA, 16 B/lane, no VGPR round-trip (kills the vmcnt-per-ds_write serialization).
// LDS dest is wave-uniform base + lane*16; source is per-lane address.
__device__ __forceinline__ void gload_lds16(const u64* g, u64* l) {
    __builtin_amdgcn_global_load_lds(
        (const __attribute__((address_space(1))) unsigned int*)(const void*)g,
        (__attribute__((address_space(3))) unsigned int*)(void*)l,
        16, 0, 0);
}

// ---------------- K1: per-block LDS histogram -> private u16 sub-hist (no global atomics) ----------------
__global__ __launch_bounds__(512) void k_hist(const float* __restrict__ logits,
                                              unsigned short* __restrict__ ghist) {
    __shared__ unsigned int h[NBINS];  // 16 KiB
    int n = blockIdx.y, b = blockIdx.x;
    for (int i = threadIdx.x; i < NBINS; i += 512) h[i] = 0;
    __syncthreads();
    const float4* lp = (const float4*)(logits + (size_t)n * M_ + (size_t)b * SEG_);
    const int nq = SEG_ / 4;                 // 2646
    for (int q = threadIdx.x; q < nq; q += 512) {
        float4 v = lp[q];
        atomicAdd(&h[flip_key(v.x) >> BIN_SHIFT], 1u);
        atomicAdd(&h[flip_key(v.y) >> BIN_SHIFT], 1u);
        atomicAdd(&h[flip_key(v.z) >> BIN_SHIFT], 1u);
        atomicAdd(&h[flip_key(v.w) >> BIN_SHIFT], 1u);
    }
    __syncthreads();
    unsigned short* gp = ghist + ((size_t)n * HBLK + b) * NBINS;
    for (int i = threadIdx.x; i < NBINS; i += 512) gp[i] = (unsigned short)h[i];
}

// ---------------- K1b: sum sub-hists, find threshold bin B per batch ----------------
__global__ __launch_bounds__(256) void k_scan(const unsigned short* __restrict__ ghist,
                                              unsigned int* __restrict__ thresh) {
    int n = blockIdx.x;
    int t = threadIdx.x;
    __shared__ unsigned int binsum[NBINS];
    __shared__ unsigned int part[256];
    __shared__ unsigned int scanb[256];
    const unsigned short* base = ghist + (size_t)n * HBLK * NBINS;
    for (int i = t; i < NBINS; i += 256) {
        unsigned int s = 0;
        #pragma unroll 8
        for (int b = 0; b < HBLK; ++b) s += base[(size_t)b * NBINS + i];
        binsum[i] = s;
    }
    __syncthreads();
    // chunk t covers bins [NBINS-16*(t+1), NBINS-16*t) — descending chunks
    int hi = NBINS - 16 * t;
    int lo = hi - 16;
    unsigned int s = 0;
    for (int b = lo; b < hi; ++b) s += binsum[b];
    part[t] = s;
    scanb[t] = s;
    __syncthreads();
    for (int off = 1; off < 256; off <<= 1) {
        unsigned int v = scanb[t];
        unsigned int addv = (t >= off) ? scanb[t - off] : 0u;
        __syncthreads();
        scanb[t] = v + addv;
        __syncthreads();
    }
    unsigned int incl = scanb[t];
    unsigned int prefix = incl - part[t];
    if (prefix < K_TOP && incl >= K_TOP) {
        unsigned int acc = prefix;
        for (int b = hi - 1; b >= lo; --b) {
            unsigned int c = binsum[b];
            if (acc + c >= K_TOP) {
                thresh[n] = (unsigned int)b;
                break;
            }
            acc += c;
        }
    }
}

// ---------------- K2: compact candidates via LDS buffer + 1 global atomic per block ----------------
__global__ __launch_bounds__(512) void k_compact(const float* __restrict__ logits,
                                                 const unsigned int* __restrict__ thresh,
                                                 unsigned int* __restrict__ cnt,
                                                 u64* __restrict__ cand) {
    __shared__ u64 buf[CAND_CAP];  // 32 KiB
    __shared__ unsigned int lcnt;
    __shared__ unsigned int gbase;
    int n = blockIdx.y, b = blockIdx.x;
    unsigned int B = thresh[n];
    if (threadIdx.x == 0) lcnt = 0;
    __syncthreads();
    const int qbase = b * SEG_;
    const float4* lp = (const float4*)(logits + (size_t)n * M_ + (size_t)qbase);
    const int nq = SEG_ / 4;
    for (int q = threadIdx.x; q < nq; q += 512) {
        float4 v = lp[q];
        float vv[4] = {v.x, v.y, v.z, v.w};
        #pragma unroll
        for (int e = 0; e < 4; ++e) {
            unsigned int u = flip_key(vv[e]);
            if ((u >> BIN_SHIFT) >= B) {
                int qq = qbase + q * 4 + e;
                int a = qq / HW_;
                int hw = qq - a * HW_;
                unsigned int m = (unsigned int)(hw * A_ + a);  // score-order index
                unsigned int pos = atomicAdd(&lcnt, 1u);
                if (pos < CAND_CAP)
                    buf[pos] = ((u64)u << 32) | (unsigned int)(~m);
            }
        }
    }
    __syncthreads();
    unsigned int L = (lcnt < CAND_CAP) ? lcnt : CAND_CAP;
    if (threadIdx.x == 0) gbase = atomicAdd(&cnt[n], L);
    __syncthreads();
    u64* cp = cand + (size_t)n * CAND_CAP;
    for (unsigned int i = threadIdx.x; i < L; i += 512) {
        unsigned int pos = gbase + i;
        if (pos < CAND_CAP) cp[pos] = buf[i];
    }
}

// ---------------- K3: rank-by-counting (replaces bitonic sort) + fused decode ----------------
// Keys are unique -> rank(i) = #{j: key_j > key_i} is a permutation; rank < K_TOP
// candidates ARE the sorted top-2000 (desc, ties by smaller m — matches lax.top_k).
__global__ __launch_bounds__(512) void k_rank(const u64* __restrict__ cand,
                                              const unsigned int* __restrict__ cnt,
                                              const float* __restrict__ anchors,
                                              const float* __restrict__ breg,
                                              float4* __restrict__ boxes,
                                              float* __restrict__ scores,
                                              float* __restrict__ areas) {
    __shared__ u64 keys[CAND_CAP];          // 32 KiB
    __shared__ unsigned short psum[512];
    int n = blockIdx.y;
    int bx = blockIdx.x;
    unsigned int Cu = cnt[n];
    int C = (Cu < CAND_CAP) ? (int)Cu : CAND_CAP;
    const u64* cp = cand + (size_t)n * CAND_CAP;
    for (int i = threadIdx.x; i < C; i += 512) keys[i] = cp[i];
    __syncthreads();
    int t = threadIdx.x;
    int ci = bx * 256 + (t & 255);
    int half = t >> 8;                       // wave-uniform (waves 0-3: 0, waves 4-7: 1)
    unsigned int r = 0;
    u64 ki = 0;
    if (ci < C) {
        ki = keys[ci];
        int j = half;
        for (; j + 6 < C; j += 8) {          // 4 accumulations/iter, independent cmps
            r += (keys[j] > ki);
            r += (keys[j + 2] > ki);
            r += (keys[j + 4] > ki);
            r += (keys[j + 6] > ki);
        }
        for (; j < C; j += 2) r += (keys[j] > ki);
    }
    psum[t] = (unsigned short)r;
    __syncthreads();
    if (t < 256 && ci < C) {
        unsigned int rank = (unsigned int)psum[t] + (unsigned int)psum[t + 256];
        if (rank < K_TOP) {
            unsigned int u = (unsigned int)(ki >> 32);
            unsigned int m = ~((unsigned int)ki);
            float logit = unflip_key(u);
            int a = (int)(m % 3u);
            int hw = (int)(m / 3u);
            float4 anc = ((const float4*)anchors)[(size_t)n * M_ + m];
            size_t rb = ((size_t)n * 12 + a * 4) * HW_ + hw;
            float dx = breg[rb];
            float dy = breg[rb + (size_t)HW_];
            float dw = breg[rb + (size_t)2 * HW_];
            float dh = breg[rb + (size_t)3 * HW_];
            float score = 1.0f / (1.0f + expf(-logit));
            float w = anc.z - anc.x + 1.0f;
            float h = anc.w - anc.y + 1.0f;
            float cx = anc.x + 0.5f * w;
            float cy = anc.y + 0.5f * h;
            dw = fminf(dw, XCLIP);
            dh = fminf(dh, XCLIP);
            float pcx = dx * w + cx;
            float pcy = dy * h + cy;
            float pw = expf(dw) * w;
            float ph = expf(dh) * h;
            float x1 = pcx - 0.5f * pw;
            float y1 = pcy - 0.5f * ph;
            float x2 = pcx + 0.5f * pw - 1.0f;
            float y2 = pcy + 0.5f * ph - 1.0f;
            x1 = fminf(fmaxf(x1, 0.0f), 1332.0f);
            y1 = fminf(fmaxf(y1, 0.0f), 799.0f);
            x2 = fminf(fmaxf(x2, 0.0f), 1332.0f);
            y2 = fminf(fmaxf(y2, 0.0f), 799.0f);
            float ww = x2 - x1 + 1.0f;
            float hh = y2 - y1 + 1.0f;
            bool keep = (ww >= 0.0f) && (hh >= 0.0f);  // MIN_SIZE = 0
            int g = n * K_TOP + (int)rank;
            boxes[g] = make_float4(x1, y1, x2, y2);
            scores[g] = keep ? score : NEG_;
            areas[g] = ww * hh;
        }
    }
}

// ---------------- K5: dense adjacency bitmask: adj[n][i][w] bit b = IoU(i, 64w+b) > thr ----------------
// NOTE: IoU is computed with fully commutative float ops -> matrix is bitwise symmetric.
// k_resolve depends on this (uses rows as columns).
#define JT 512   // j's per block tile (8 u64 words)
#define RT 64    // rows per block tile
__global__ __launch_bounds__(256) void k_edges(const float4* __restrict__ boxes,
                                               const float* __restrict__ areas,
                                               u64* __restrict__ adj) {
    __shared__ float4 jb[JT];
    __shared__ float ja[JT];
    int n = blockIdx.z;
    int r0 = blockIdx.y * RT;
    int j0 = blockIdx.x * JT;
    for (int j = threadIdx.x; j < JT; j += 256) {
        int jj = j0 + j;
        if (jj < K_TOP) {
            jb[j] = boxes[(size_t)n * K_TOP + jj];
            ja[j] = areas[(size_t)n * K_TOP + jj];
        } else {
            jb[j] = make_float4(-1e8f, -1e8f, -1e8f, -1e8f);  // IoU vs anything = 0
            ja[j] = 0.0f;
        }
    }
    __syncthreads();
    int i = r0 + (threadIdx.x >> 2);       // 4 threads per row
    if (i >= K_TOP) return;
    float4 bi = boxes[(size_t)n * K_TOP + i];
    float ai = areas[(size_t)n * K_TOP + i];
    #pragma unroll
    for (int rep = 0; rep < 2; ++rep) {
        int wl = (threadIdx.x & 3) + rep * 4;  // word-in-tile 0..7
        u64 bits = 0;
        int base = wl * 64;
        #pragma unroll 8
        for (int b = 0; b < 64; ++b) {
            float4 bj = jb[base + b];
            float xx1 = fmaxf(bi.x, bj.x);
            float yy1 = fmaxf(bi.y, bj.y);
            float xx2 = fminf(bi.z, bj.z);
            float yy2 = fminf(bi.w, bj.w);
            float inter = fmaxf(xx2 - xx1 + 1.0f, 0.0f) * fmaxf(yy2 - yy1 + 1.0f, 0.0f);
            float iou = inter / (ai + ja[base + b] - inter);
            bits |= ((u64)(iou > NMS_THR_)) << b;
        }
        adj[((size_t)n * NPAD + i) * NW + (j0 >> 6) + wl] = bits;
    }
}

// ---------------- K6: wave-specialized greedy NMS; prefetch via global_load_lds DMA ----------------
// R9 lesson: the 82 µs floor across three resolve structures was the prefetch loop's
// load->ds_write serialization (vmcnt(0) drain per iteration x ~900 cyc HBM latency).
// global_load_lds removes the VGPR round-trip: 16 DMA issues/chunk, ONE waitcnt, release.
__global__ __launch_bounds__(256) void k_resolve(const float4* __restrict__ boxes,
                                                 const float* __restrict__ scores,
                                                 const u64* __restrict__ adj,
                                                 float* __restrict__ out) {
    __shared__ u64 ring[RING][64 * NW];     // 4 x 16 KiB = 64 KiB, CONTIGUOUS (DMA layout)
    __shared__ float sls[NPAD];             // 8 KiB
    __shared__ unsigned char alive[NPAD];   // 2 KiB (indices >= K_TOP stay 0)
    __shared__ int list[64];                // alive indices of current chunk (resolver-wave private)
    __shared__ int ready[RING];             // slot s holds chunk c when ready[s]==c+1
    __shared__ int progress;                // # chunks fully resolved
    __shared__ unsigned int scanbuf[256];
    int n = blockIdx.x;
    int tid = threadIdx.x;
    int wave = tid >> 6, lane = tid & 63;
    const u64* ab = adj + (size_t)n * NPAD * NW;

    for (int i = tid; i < NPAD; i += 256) {
        sls[i] = (i < K_TOP) ? scores[(size_t)n * K_TOP + i] : NEG_;
        alive[i] = 0;
    }
    if (tid < RING) ready[tid] = 0;
    if (tid == 0) progress = 0;
    __syncthreads();  // init visible to all waves (the ONLY barrier before the epilogue)

    if (wave == 0) {
        // ---- resolver ----
        u64 supreg = 0;  // lane w (w<32) holds suppressed-mask word w
        for (int c = 0; c < NCHUNK; ++c) {
            int slot = c & (RING - 1);
            while (__hip_atomic_load(&ready[slot], __ATOMIC_ACQUIRE,
                                     __HIP_MEMORY_SCOPE_WORKGROUP) != c + 1)
                __builtin_amdgcn_s_sleep(1);
            int k = lane;
            int gi = c * 64 + k;
            // symmetric adjacency: row gi word c == column k of the diag block
            // (stride NW=32 u64 -> 32-way bank aliasing on this one read; once per chunk, acceptable)
            u64 colk = ring[slot][k * NW + c];
            u64 supc = __shfl(supreg, c, 64);
            bool validk = (sls[gi] > VALID_THR_) && !((supc >> k) & 1ull);
            u64 below = (k == 0) ? 0ull : ((1ull << k) - 1ull);
            u64 rel = colk & below;
            // ballot-Jacobi: well-founded in k -> unique fixed point == greedy result
            bool a = validk;
            u64 am = __ballot(a);
            while (true) {
                bool anew = validk && ((am & rel) == 0ull);
                u64 am2 = __ballot(anew);
                if (am2 == am) { a = anew; break; }
                am = am2;
            }
            alive[gi] = a ? 1 : 0;
            if (a) list[__popcll(am & below)] = k;
            int nal = (int)__popcll(am);
            // sup-OR inside resolver wave: lane = half*32 + w
            int w = lane & 31, half = lane >> 5;
            u64 acc = 0;
            for (int i = half; i < nal; i += 2)
                acc |= ring[slot][list[i] * NW + w];
            acc |= __shfl_down(acc, 32);    // fold half 1 into half 0
            if (lane < 32) supreg |= acc;
            if (lane == 0)
                __hip_atomic_store(&progress, c + 1, __ATOMIC_RELEASE,
                                   __HIP_MEMORY_SCOPE_WORKGROUP);
        }
    } else {
        // ---- prefetchers: wave v handles chunks v-1, v+2, v+5, ... ----
        for (int c = wave - 1; c < NCHUNK; c += 3) {
            int slot = c & (RING - 1);
            // slot free once chunk c-4 consumed: progress >= c-3
            while (__hip_atomic_load(&progress, __ATOMIC_ACQUIRE,
                                     __HIP_MEMORY_SCOPE_WORKGROUP) < c - 3)
                __builtin_amdgcn_s_sleep(1);
            const u64* src = ab + (size_t)c * 64 * NW + lane * 2;  // 16 B per lane
            u64* dst = &ring[slot][0];
            #pragma unroll
            for (int it = 0; it < 16; ++it)   // 16 x 1 KiB DMA, back-to-back, no VGPR round-trip
                gload_lds16(src + (size_t)it * 128, dst + it * 128);
            __builtin_amdgcn_s_waitcnt(0);    // drain this wave's DMA (vmcnt) before publishing
            if (lane == 0)
                __hip_atomic_store(&ready[slot], c + 1, __ATOMIC_RELEASE,
                                   __HIP_MEMORY_SCOPE_WORKGROUP);
        }
    }
    __syncthreads();

    // --- order-preserving compaction of survivors -> output rows ---
    // i0 covers [0,2048): all arrays are NPAD-sized and alive[>=K_TOP]==0 (R3 lesson).
    int i0 = tid * 8;
    unsigned int c2 = 0;
    for (int i = i0; i < i0 + 8; ++i) c2 += alive[i];
    scanbuf[tid] = c2;
    __syncthreads();
    for (int off = 1; off < 256; off <<= 1) {
        unsigned int v = scanbuf[tid];
        unsigned int addv = (tid >= off) ? scanbuf[tid - off] : 0u;
        __syncthreads();
        scanbuf[tid] = v + addv;
        __syncthreads();
    }
    unsigned int r = scanbuf[tid] - c2;
    unsigned int total = scanbuf[255];
    float* op = out + (size_t)n * POST_N * 5;
    const float4* bb = boxes + (size_t)n * K_TOP;
    for (int i = i0; i < i0 + 8; ++i) {
        if (alive[i]) {
            if (r < POST_N) {
                float4 b = bb[i];
                op[r * 5 + 0] = b.x;
                op[r * 5 + 1] = b.y;
                op[r * 5 + 2] = b.z;
                op[r * 5 + 3] = b.w;
                op[r * 5 + 4] = sls[i];
            }
            r++;
        }
    }
    unsigned int S = (total > POST_N) ? POST_N : total;
    for (unsigned int q = S + tid; q < POST_N; q += 256) {
        op[q * 5 + 0] = 0.0f;
        op[q * 5 + 1] = 0.0f;
        op[q * 5 + 2] = 0.0f;
        op[q * 5 + 3] = 0.0f;
        op[q * 5 + 4] = 0.0f;
    }
}

extern "C" void kernel_launch(void* const* d_in, const int* in_sizes, int n_in,
                              void* d_out, int out_size, void* d_ws, size_t ws_size,
                              hipStream_t stream) {
    const float* anchors = (const float*)d_in[0];
    const float* logits  = (const float*)d_in[1];
    const float* breg    = (const float*)d_in[2];
    float* out = (float*)d_out;
    char* ws = (char*)d_ws;

    // ws layout (bytes) — adj ALIASES ghist+cand (both dead before k_edges writes adj):
    // [0, 32)               cnt    : u32[8]              (zeroed each launch)
    // [64, 96)              thresh : u32[8]              (written by k_scan)
    // [128, 2097280)        ghist  : u16[8][HBLK=32][4096]   \ dead after k_scan / k_rank
    // [2097280, 2359424)    cand   : u64[8][4096]            /
    // [128, 4194432)        adj    : u64[8][2048][32]    (written by k_edges after k_rank)
    // [4194432, 4450432)    boxes  : float4[8][2000]
    // [4450432, 4514432)    scores : f32[8][2000]
    // [4514432, 4578432)    areas  : f32[8][2000]
    unsigned int* cnt     = (unsigned int*)(ws);
    unsigned int* thresh  = (unsigned int*)(ws + 64);
    unsigned short* ghist = (unsigned short*)(ws + 128);
    u64* cand             = (u64*)(ws + 2097280);
    u64* adj              = (u64*)(ws + 128);
    float4* boxes         = (float4*)(ws + 4194432);
    float* scores         = (float*)(ws + 4450432);
    float* areas          = (float*)(ws + 4514432);

    hipMemsetAsync(ws, 0, 96, stream);

    k_hist<<<dim3(HBLK, 8), 512, 0, stream>>>(logits, ghist);
    k_scan<<<8, 256, 0, stream>>>(ghist, thresh);
    k_compact<<<dim3(HBLK, 8), 512, 0, stream>>>(logits, thresh, cnt, cand);
    k_rank<<<dim3(16, 8), 512, 0, stream>>>(cand, cnt, anchors, breg, boxes, scores, areas);
    k_edges<<<dim3(NPAD / JT, NPAD / RT, 8), 256, 0, stream>>>(boxes, areas, adj);
    k_resolve<<<8, 256, 0, stream>>>(boxes, scores, adj, out);
}